// Round 12
// baseline (105.226 us; speedup 1.0000x reference)
//
#include <hip/hip_runtime.h>

// ---------------------------------------------------------------------------
// DSTDGC R12.
// k0_stream: x -> xbf bf16 + m1g/m2g [n][k][v] projections (proven).
// k0b_T:     m1g/m2g [n][k][v] -> m1T/m2T [n][v][k]  (tiny transpose).
// k1: adjm[n][t][i][j] = alpha * (w_rm @ tanh(m1-m2))   (bf16, raw: no A,
//     no b_rm -> no gathers).  m2 staged coalesced-from-m2T, w_rm staged
//     bf16*alpha in LDS.  chunk 8 / 512 thr / grid 512, no Ast.
// k2: adj = adjm + A[t] + alpha*b_rm[t] (A[t] contiguous, L2-hot), then
//     P = adj @ x (ones-col -> rowsum), out = W_aug @ P + b_f via k=64 col.
// ---------------------------------------------------------------------------

typedef float  f32x4  __attribute__((ext_vector_type(4)));
typedef short  bf16x8 __attribute__((ext_vector_type(8)));
typedef short  bf16x4 __attribute__((ext_vector_type(4)));

static __device__ __forceinline__ short f2bf(float f) {
    unsigned u = __float_as_uint(f);
    unsigned r = (u + 0x7FFFu + ((u >> 16) & 1u)) >> 16;   // RNE
    return (short)r;
}

static __device__ __forceinline__ float bf2f(short s) {
    return __uint_as_float(((unsigned)(unsigned short)s) << 16);
}

static __device__ __forceinline__ bf16x8 cvt8f(const float4 a, const float4 b) {
    bf16x8 r;
    r[0] = f2bf(a.x); r[1] = f2bf(a.y); r[2] = f2bf(a.z); r[3] = f2bf(a.w);
    r[4] = f2bf(b.x); r[5] = f2bf(b.y); r[6] = f2bf(b.z); r[7] = f2bf(b.w);
    return r;
}

static __device__ __forceinline__ bf16x8 cvt8(const float* p) {
    return cvt8f(*(const float4*)p, *(const float4*)(p + 4));
}

// tanh(x) = 1 - 2/(exp(2x)+1)
static __device__ __forceinline__ float tanh_fast(float x) {
    float e = __expf(2.0f * x);
    return 1.0f - 2.0f * __builtin_amdgcn_rcpf(e + 1.0f);
}

static __device__ __forceinline__ float dot4(float4 a, float4 b) {
    return a.x * b.x + a.y * b.y + a.z * b.z + a.w * b.w;
}

static __device__ __forceinline__ float alpha_decode(const int* p) {
    int raw = p[0];
    unsigned ur = (unsigned)(raw < 0 ? -raw : raw);
    return (ur < (1u << 23)) ? (float)raw : __int_as_float(raw);
}

#define MFMA16(a, b, c) __builtin_amdgcn_mfma_f32_16x16x32_bf16((a), (b), (c), 0, 0, 0)

// ---------------------------------------------------------------------------
// K0_stream: 8 threads per row (n,t,v).  Coalesced 16B in/out, no LDS.
// ---------------------------------------------------------------------------
__global__ __launch_bounds__(256) void k0_stream(
    const float* __restrict__ x,
    const float* __restrict__ w_m1, const float* __restrict__ b_m1,
    const float* __restrict__ w_m2, const float* __restrict__ b_m2,
    short* __restrict__ xbf, float* __restrict__ m1g, float* __restrict__ m2g)
{
    const int g  = blockIdx.x * 256 + threadIdx.x;
    const int R  = g >> 3;
    const int l8 = g & 7;
    const int c0 = l8 * 8;
    const int n  = R >> 12, tt = (R >> 6) & 63, v = R & 63;

    const float* xp = x + ((size_t)R << 6) + c0;
    const float4 a0 = *(const float4*)xp;
    const float4 a1 = *(const float4*)(xp + 4);

    float s0 = dot4(a0, *(const float4*)(w_m1 + c0))
             + dot4(a1, *(const float4*)(w_m1 + c0 + 4));
    float s1 = dot4(a0, *(const float4*)(w_m1 + 64 + c0))
             + dot4(a1, *(const float4*)(w_m1 + 64 + c0 + 4));
    float s2 = dot4(a0, *(const float4*)(w_m2 + c0))
             + dot4(a1, *(const float4*)(w_m2 + c0 + 4));
    float s3 = dot4(a0, *(const float4*)(w_m2 + 64 + c0))
             + dot4(a1, *(const float4*)(w_m2 + 64 + c0 + 4));

    *(bf16x8*)(xbf + ((size_t)R << 6) + c0) = cvt8f(a0, a1);

#pragma unroll
    for (int m = 1; m < 8; m <<= 1) {
        s0 += __shfl_xor(s0, m);
        s1 += __shfl_xor(s1, m);
        s2 += __shfl_xor(s2, m);
        s3 += __shfl_xor(s3, m);
    }
    if (l8 < 4) {
        float s    = (l8 == 0) ? s0 : (l8 == 1) ? s1 : (l8 == 2) ? s2 : s3;
        float bias = (l8 < 2) ? b_m1[l8] : b_m2[l8 - 2];
        float* base = (l8 < 2) ? m1g : m2g;
        base[n * 8192 + ((l8 & 1) * 64 + tt) * 64 + v] = s + bias;
    }
}

// ---------------------------------------------------------------------------
// K0b: transpose m1g/m2g [n][k][v] -> m1T/m2T [n][v][k].  grid 1024x256.
// ---------------------------------------------------------------------------
__global__ __launch_bounds__(256) void k0b_T(
    const float* __restrict__ m1g, const float* __restrict__ m2g,
    float* __restrict__ m1T, float* __restrict__ m2T)
{
    const int idx   = blockIdx.x * 256 + threadIdx.x;   // 0..262143 (f4 of out)
    const int which = idx >> 17;                        // 0: m1, 1: m2
    const int r     = idx & 131071;
    const int n     = r >> 11;
    const int rr    = r & 2047;
    const int v     = rr >> 5;
    const int k0    = (rr & 31) * 4;

    const float* s = (which ? m2g : m1g) + n * 8192 + v;
    float4 o;
    o.x = s[(k0 + 0) * 64];
    o.y = s[(k0 + 1) * 64];
    o.z = s[(k0 + 2) * 64];
    o.w = s[(k0 + 3) * 64];
    float* d = (which ? m2T : m1T) + n * 8192 + v * 128 + k0;
    *(float4*)d = o;
}

// ---------------------------------------------------------------------------
// K1: block (n, i-chunk of 8), 512 thr, grid 512.
//   adjm[n][t][i][j] = alpha * sum_k w_rm[t,k] tanh(m1[i,k]-m2[j,k])  (bf16)
// ---------------------------------------------------------------------------
__global__ __launch_bounds__(512) void k1_adj(
    const float* __restrict__ w_rm,
    const float* __restrict__ m1T,  const float* __restrict__ m2T,
    const int* __restrict__ alpha_p,
    short* __restrict__ adjm)
{
    __shared__ float m2s[64 * 132];     // [j][k] f32 stride 132     (33.8 KB)
    __shared__ short wrs[64 * 136];     // [t][k] bf16*alpha, s=136  (17.4 KB)

    const int b   = blockIdx.x;
    const int n   = b >> 3;
    const int i0  = (b & 7) * 8;
    const int tid = threadIdx.x;

    const float alpha = alpha_decode(alpha_p);

    // stage m2[n]: m2T [v][k] -> LDS [j][k], float4 both sides
    {
        const float4* src = (const float4*)(m2T + n * 8192);
        for (int it = tid; it < 2048; it += 512) {
            int j = it >> 5, q = it & 31;
            *(float4*)(m2s + j * 132 + q * 4) = src[it];
        }
    }
    // stage w_rm * alpha as bf16 [t][k]
    {
        const float4* src = (const float4*)w_rm;
        for (int it = tid; it < 2048; it += 512) {
            int t = it >> 5, q = it & 31;
            float4 v = src[it];
            bf16x4 pv;
            pv[0] = f2bf(alpha * v.x);
            pv[1] = f2bf(alpha * v.y);
            pv[2] = f2bf(alpha * v.z);
            pv[3] = f2bf(alpha * v.w);
            *(bf16x4*)(wrs + t * 136 + q * 4) = pv;
        }
    }
    __syncthreads();

    const int l = tid & 63, w = tid >> 6;
    const int lr = l & 15, lg = l >> 4;
    const int ig = i0 + w;

    // m1 row for this wave's i: wave-broadcast global reads -> 32 VGPR
    float4 m1r[8];
#pragma unroll
    for (int kt = 0; kt < 4; ++kt) {
        const float* p = m1T + n * 8192 + ig * 128 + kt * 32 + lg * 8;
        m1r[kt * 2 + 0] = *(const float4*)p;
        m1r[kt * 2 + 1] = *(const float4*)(p + 4);
    }

    short* adjb = adjm + ((size_t)n << 18) + (ig << 6);

#pragma unroll 1
    for (int jt = 0; jt < 4; ++jt) {
        const float* m2row = m2s + (jt * 16 + lr) * 132;
        bf16x8 bfr[4];
#pragma unroll
        for (int kt = 0; kt < 4; ++kt) {
            const int k0 = kt * 32 + lg * 8;
            float4 b0 = *(const float4*)(m2row + k0);
            float4 b1 = *(const float4*)(m2row + k0 + 4);
            float4 a0 = m1r[kt * 2], a1 = m1r[kt * 2 + 1];
            bfr[kt][0] = f2bf(tanh_fast(a0.x - b0.x));
            bfr[kt][1] = f2bf(tanh_fast(a0.y - b0.y));
            bfr[kt][2] = f2bf(tanh_fast(a0.z - b0.z));
            bfr[kt][3] = f2bf(tanh_fast(a0.w - b0.w));
            bfr[kt][4] = f2bf(tanh_fast(a1.x - b1.x));
            bfr[kt][5] = f2bf(tanh_fast(a1.y - b1.y));
            bfr[kt][6] = f2bf(tanh_fast(a1.z - b1.z));
            bfr[kt][7] = f2bf(tanh_fast(a1.w - b1.w));
        }

        const int j0 = jt * 16 + lg * 4;
#pragma unroll
        for (int q = 0; q < 4; ++q) {
            const int tq = q * 16 + lr;
            bf16x8 af[4];
#pragma unroll
            for (int kt = 0; kt < 4; ++kt)
                af[kt] = *(const bf16x8*)(wrs + tq * 136 + kt * 32 + lg * 8);
            f32x4 acc = (f32x4){0.f, 0.f, 0.f, 0.f};
#pragma unroll
            for (int kt = 0; kt < 4; ++kt)
                acc = MFMA16(bfr[kt], af[kt], acc);             // D[j][t]
            bf16x4 pv;
            pv[0] = f2bf(acc[0]);
            pv[1] = f2bf(acc[1]);
            pv[2] = f2bf(acc[2]);
            pv[3] = f2bf(acc[3]);
            *(bf16x4*)(adjb + ((size_t)tq << 12) + j0) = pv;    // 8B store
        }
    }
}

// ---------------------------------------------------------------------------
// K2: block = one (n,t), 4 waves.  adj = adjm + A[t] + alpha*b_rm[t] (A[t]
//   contiguous/L2-hot), P = adj @ x (ones-col -> rowsum), out = W_aug @ P.
// ---------------------------------------------------------------------------
__global__ __launch_bounds__(256) void k2_out(
    const short* __restrict__ adjm, const short* __restrict__ xbf,
    const float* __restrict__ Ast,  const float* __restrict__ b_rm,
    const int* __restrict__ alpha_p,
    const float* __restrict__ w_f,  const float* __restrict__ b_f,
    float* __restrict__ out)
{
    __shared__ short xT[64 * 72];       // [c][j] bf16, stride 72   (9.2 KB)
    __shared__ short P[64 * 104];       // [i][c] bf16, stride 104 (13.3 KB)

    const int pair = blockIdx.x;        // n*64 + t
    const int t    = pair & 63;
    const int tid  = threadIdx.x;
    const int l = tid & 63, w = tid >> 6;
    const int lr = l & 15, lg = l >> 4;

    const short* Ab = adjm + ((size_t)pair << 12);
    const short* Xb = xbf  + ((size_t)pair << 12);
    const float* At = Ast  + ((size_t)t << 12);
    float*       Ob = out  + ((size_t)pair << 12);

    const float ab = alpha_decode(alpha_p) * b_rm[t];

    // adj A-fragments: adjm (bf16) + A[t] (f32, contiguous rows) + ab
    bf16x8 adjA[4][2];
#pragma unroll
    for (int mt = 0; mt < 4; ++mt)
#pragma unroll
        for (int ks = 0; ks < 2; ++ks) {
            const int off = (mt * 16 + lr) * 64 + ks * 32 + lg * 8;
            bf16x8 s = *(const bf16x8*)(Ab + off);
            float4 a0 = *(const float4*)(At + off);
            float4 a1 = *(const float4*)(At + off + 4);
            bf16x8 r;
            r[0] = f2bf(bf2f(s[0]) + a0.x + ab);
            r[1] = f2bf(bf2f(s[1]) + a0.y + ab);
            r[2] = f2bf(bf2f(s[2]) + a0.z + ab);
            r[3] = f2bf(bf2f(s[3]) + a0.w + ab);
            r[4] = f2bf(bf2f(s[4]) + a1.x + ab);
            r[5] = f2bf(bf2f(s[5]) + a1.y + ab);
            r[6] = f2bf(bf2f(s[6]) + a1.z + ab);
            r[7] = f2bf(bf2f(s[7]) + a1.w + ab);
            adjA[mt][ks] = r;
        }

    // stage xT[c][j] from xbf[j][c]
    {
        const int j  = tid >> 2;
        const int c0 = (tid & 3) * 16;
        bf16x8 r0 = *(const bf16x8*)(Xb + j * 64 + c0);
        bf16x8 r1 = *(const bf16x8*)(Xb + j * 64 + c0 + 8);
#pragma unroll
        for (int d = 0; d < 8; ++d) {
            xT[(c0 + d) * 72 + j]     = r0[d];
            xT[(c0 + 8 + d) * 72 + j] = r1[d];
        }
    }
    if (tid < 128) {
        int row = tid >> 1, cz = 80 + (tid & 1) * 8;
        bf16x8 z = {0, 0, 0, 0, 0, 0, 0, 0};
        *(bf16x8*)(P + row * 104 + cz) = z;
    }
    __syncthreads();

    // Phase 1: P = adj @ x  (wave w -> c-tile w); wave 0 adds ones-col tile
    {
        bf16x8 bx[2];
#pragma unroll
        for (int ks = 0; ks < 2; ++ks)
            bx[ks] = *(const bf16x8*)(xT + (w * 16 + lr) * 72 + ks * 32 + lg * 8);

        f32x4 acc[4];
#pragma unroll
        for (int mt = 0; mt < 4; ++mt) acc[mt] = (f32x4){0.f, 0.f, 0.f, 0.f};
#pragma unroll
        for (int ks = 0; ks < 2; ++ks)
#pragma unroll
            for (int mt = 0; mt < 4; ++mt)
                acc[mt] = MFMA16(adjA[mt][ks], bx[ks], acc[mt]);   // D[i][c]

#pragma unroll
        for (int mt = 0; mt < 4; ++mt)
#pragma unroll
            for (int e = 0; e < 4; ++e)
                P[(mt * 16 + lg * 4 + e) * 104 + w * 16 + lr] = f2bf(acc[mt][e]);

        if (w == 0) {
            bf16x8 ones = {0, 0, 0, 0, 0, 0, 0, 0};
            if (lr == 0) {
#pragma unroll
                for (int d = 0; d < 8; ++d) ones[d] = (short)0x3F80;
            }
            f32x4 accO[4];
#pragma unroll
            for (int mt = 0; mt < 4; ++mt) accO[mt] = (f32x4){0.f, 0.f, 0.f, 0.f};
#pragma unroll
            for (int ks = 0; ks < 2; ++ks)
#pragma unroll
                for (int mt = 0; mt < 4; ++mt)
                    accO[mt] = MFMA16(adjA[mt][ks], ones, accO[mt]);
#pragma unroll
            for (int mt = 0; mt < 4; ++mt)
#pragma unroll
                for (int e = 0; e < 4; ++e)
                    P[(mt * 16 + lg * 4 + e) * 104 + 64 + lr] = f2bf(accO[mt][e]);
        }
    }
    __syncthreads();

    // Phase 2: out = W_aug @ P  (wave w -> o-tile w), b_f as k=64 column
    {
        const int o = w * 16 + lr;
        bf16x8 afw[3];
#pragma unroll
        for (int ks = 0; ks < 2; ++ks)
            afw[ks] = cvt8(w_f + o * 64 + ks * 32 + lg * 8);
        {
            bf16x8 ab2 = {0, 0, 0, 0, 0, 0, 0, 0};
            if (lg == 0) ab2[0] = f2bf(b_f[o]);
            afw[2] = ab2;
        }

#pragma unroll
        for (int nt = 0; nt < 4; ++nt) {
            const int i = nt * 16 + lr;
            bf16x8 bP[3];
#pragma unroll
            for (int ks = 0; ks < 3; ++ks)
                bP[ks] = *(const bf16x8*)(P + i * 104 + ks * 32 + lg * 8);
            f32x4 acc = (f32x4){0.f, 0.f, 0.f, 0.f};
#pragma unroll
            for (int ks = 0; ks < 3; ++ks)
                acc = MFMA16(afw[ks], bP[ks], acc);             // D[o][i]
            *(f32x4*)(Ob + i * 64 + w * 16 + lg * 4) = acc;
        }
    }
}

// ---------------------------------------------------------------------------
extern "C" void kernel_launch(void* const* d_in, const int* in_sizes, int n_in,
                              void* d_out, int out_size, void* d_ws, size_t ws_size,
                              hipStream_t stream)
{
    const float* x    = (const float*)d_in[0];
    const float* A    = (const float*)d_in[1];
    const float* w_m1 = (const float*)d_in[2];
    const float* b_m1 = (const float*)d_in[3];
    const float* w_m2 = (const float*)d_in[4];
    const float* b_m2 = (const float*)d_in[5];
    const float* w_rm = (const float*)d_in[6];
    const float* b_rm = (const float*)d_in[7];
    const float* w_f  = (const float*)d_in[8];
    const float* b_f  = (const float*)d_in[9];
    const int*   alpha = (const int*)d_in[10];

    // ws layout (temporal overlay: m1g/m2g dead after k0b; adjm reuses them):
    //   [0,2MB)    m1g [n][k][v]      (k0_stream -> k0b)
    //   [2,4MB)    m2g [n][k][v]      (k0_stream -> k0b)
    //   [0,33.5MB) adjm bf16          (k1 -> k2, AFTER k0b consumed m1g/m2g)
    //   [34,66MB)  xbf bf16
    //   [66,68MB)  m1T [n][v][k]
    //   [68,70MB)  m2T [n][v][k]
    char* ws = (char*)d_ws;
    float* m1g = (float*)(ws);
    float* m2g = (float*)(ws + (size_t)2 * 1024 * 1024);
    short* adjm = (short*)(ws);
    short* xbf = (short*)(ws + (size_t)34 * 1024 * 1024);
    float* m1T = (float*)(ws + (size_t)66 * 1024 * 1024);
    float* m2T = (float*)(ws + (size_t)68 * 1024 * 1024);
    float* out = (float*)d_out;

    k0_stream<<<dim3(8192), dim3(256), 0, stream>>>(x, w_m1, b_m1, w_m2, b_m2,
                                                    xbf, m1g, m2g);
    k0b_T<<<dim3(1024), dim3(256), 0, stream>>>(m1g, m2g, m1T, m2T);
    k1_adj<<<dim3(512), dim3(512), 0, stream>>>(w_rm, m1T, m2T, alpha, adjm);
    k2_out<<<dim3(4096), dim3(256), 0, stream>>>(adjm, xbf, A, b_rm, alpha,
                                                 w_f, b_f, out);
}

// Round 14
// 74.280 us; speedup vs baseline: 1.4166x; 1.4166x over previous
//
#include <hip/hip_runtime.h>

// ---------------------------------------------------------------------------
// DSTDGC R14 (= R13 resubmitted: container died before evaluation).
// k0_stream / k0b_T / k1: unchanged from R12 (k1 restructure proven good).
// k2: all former gathers (adjm fragments, A[t] fragments) replaced by ONE
//     coalesced LDS staging pass that also fuses adj = adjm + A[t] + a*b_rm.
//     xT staging uses group-padded layout (kills the 4-way bank collapse).
// ---------------------------------------------------------------------------

typedef float  f32x4  __attribute__((ext_vector_type(4)));
typedef short  bf16x8 __attribute__((ext_vector_type(8)));
typedef short  bf16x4 __attribute__((ext_vector_type(4)));

static __device__ __forceinline__ short f2bf(float f) {
    unsigned u = __float_as_uint(f);
    unsigned r = (u + 0x7FFFu + ((u >> 16) & 1u)) >> 16;   // RNE
    return (short)r;
}

static __device__ __forceinline__ float bf2f(short s) {
    return __uint_as_float(((unsigned)(unsigned short)s) << 16);
}

static __device__ __forceinline__ bf16x8 cvt8f(const float4 a, const float4 b) {
    bf16x8 r;
    r[0] = f2bf(a.x); r[1] = f2bf(a.y); r[2] = f2bf(a.z); r[3] = f2bf(a.w);
    r[4] = f2bf(b.x); r[5] = f2bf(b.y); r[6] = f2bf(b.z); r[7] = f2bf(b.w);
    return r;
}

static __device__ __forceinline__ bf16x8 cvt8(const float* p) {
    return cvt8f(*(const float4*)p, *(const float4*)(p + 4));
}

// tanh(x) = 1 - 2/(exp(2x)+1)
static __device__ __forceinline__ float tanh_fast(float x) {
    float e = __expf(2.0f * x);
    return 1.0f - 2.0f * __builtin_amdgcn_rcpf(e + 1.0f);
}

static __device__ __forceinline__ float dot4(float4 a, float4 b) {
    return a.x * b.x + a.y * b.y + a.z * b.z + a.w * b.w;
}

static __device__ __forceinline__ float alpha_decode(const int* p) {
    int raw = p[0];
    unsigned ur = (unsigned)(raw < 0 ? -raw : raw);
    return (ur < (1u << 23)) ? (float)raw : __int_as_float(raw);
}

#define MFMA16(a, b, c) __builtin_amdgcn_mfma_f32_16x16x32_bf16((a), (b), (c), 0, 0, 0)

// ---------------------------------------------------------------------------
// K0_stream: 8 threads per row (n,t,v).  Coalesced 16B in/out, no LDS.
// ---------------------------------------------------------------------------
__global__ __launch_bounds__(256) void k0_stream(
    const float* __restrict__ x,
    const float* __restrict__ w_m1, const float* __restrict__ b_m1,
    const float* __restrict__ w_m2, const float* __restrict__ b_m2,
    short* __restrict__ xbf, float* __restrict__ m1g, float* __restrict__ m2g)
{
    const int g  = blockIdx.x * 256 + threadIdx.x;
    const int R  = g >> 3;
    const int l8 = g & 7;
    const int c0 = l8 * 8;
    const int n  = R >> 12, tt = (R >> 6) & 63, v = R & 63;

    const float* xp = x + ((size_t)R << 6) + c0;
    const float4 a0 = *(const float4*)xp;
    const float4 a1 = *(const float4*)(xp + 4);

    float s0 = dot4(a0, *(const float4*)(w_m1 + c0))
             + dot4(a1, *(const float4*)(w_m1 + c0 + 4));
    float s1 = dot4(a0, *(const float4*)(w_m1 + 64 + c0))
             + dot4(a1, *(const float4*)(w_m1 + 64 + c0 + 4));
    float s2 = dot4(a0, *(const float4*)(w_m2 + c0))
             + dot4(a1, *(const float4*)(w_m2 + c0 + 4));
    float s3 = dot4(a0, *(const float4*)(w_m2 + 64 + c0))
             + dot4(a1, *(const float4*)(w_m2 + 64 + c0 + 4));

    *(bf16x8*)(xbf + ((size_t)R << 6) + c0) = cvt8f(a0, a1);

#pragma unroll
    for (int m = 1; m < 8; m <<= 1) {
        s0 += __shfl_xor(s0, m);
        s1 += __shfl_xor(s1, m);
        s2 += __shfl_xor(s2, m);
        s3 += __shfl_xor(s3, m);
    }
    if (l8 < 4) {
        float s    = (l8 == 0) ? s0 : (l8 == 1) ? s1 : (l8 == 2) ? s2 : s3;
        float bias = (l8 < 2) ? b_m1[l8] : b_m2[l8 - 2];
        float* base = (l8 < 2) ? m1g : m2g;
        base[n * 8192 + ((l8 & 1) * 64 + tt) * 64 + v] = s + bias;
    }
}

// ---------------------------------------------------------------------------
// K0b: transpose m1g/m2g [n][k][v] -> m1T/m2T [n][v][k].
// ---------------------------------------------------------------------------
__global__ __launch_bounds__(256) void k0b_T(
    const float* __restrict__ m1g, const float* __restrict__ m2g,
    float* __restrict__ m1T, float* __restrict__ m2T)
{
    const int idx   = blockIdx.x * 256 + threadIdx.x;
    const int which = idx >> 17;
    const int r     = idx & 131071;
    const int n     = r >> 11;
    const int rr    = r & 2047;
    const int v     = rr >> 5;
    const int k0    = (rr & 31) * 4;

    const float* s = (which ? m2g : m1g) + n * 8192 + v;
    float4 o;
    o.x = s[(k0 + 0) * 64];
    o.y = s[(k0 + 1) * 64];
    o.z = s[(k0 + 2) * 64];
    o.w = s[(k0 + 3) * 64];
    float* d = (which ? m2T : m1T) + n * 8192 + v * 128 + k0;
    *(float4*)d = o;
}

// ---------------------------------------------------------------------------
// K1: block (n, i-chunk of 8), 512 thr, grid 512.
//   adjm[n][t][i][j] = alpha * sum_k w_rm[t,k] tanh(m1[i,k]-m2[j,k])  (bf16)
// ---------------------------------------------------------------------------
__global__ __launch_bounds__(512) void k1_adj(
    const float* __restrict__ w_rm,
    const float* __restrict__ m1T,  const float* __restrict__ m2T,
    const int* __restrict__ alpha_p,
    short* __restrict__ adjm)
{
    __shared__ float m2s[64 * 132];     // [j][k] f32 stride 132     (33.8 KB)
    __shared__ short wrs[64 * 136];     // [t][k] bf16*alpha, s=136  (17.4 KB)

    const int b   = blockIdx.x;
    const int n   = b >> 3;
    const int i0  = (b & 7) * 8;
    const int tid = threadIdx.x;

    const float alpha = alpha_decode(alpha_p);

    {
        const float4* src = (const float4*)(m2T + n * 8192);
        for (int it = tid; it < 2048; it += 512) {
            int j = it >> 5, q = it & 31;
            *(float4*)(m2s + j * 132 + q * 4) = src[it];
        }
    }
    {
        const float4* src = (const float4*)w_rm;
        for (int it = tid; it < 2048; it += 512) {
            int t = it >> 5, q = it & 31;
            float4 v = src[it];
            bf16x4 pv;
            pv[0] = f2bf(alpha * v.x);
            pv[1] = f2bf(alpha * v.y);
            pv[2] = f2bf(alpha * v.z);
            pv[3] = f2bf(alpha * v.w);
            *(bf16x4*)(wrs + t * 136 + q * 4) = pv;
        }
    }
    __syncthreads();

    const int l = tid & 63, w = tid >> 6;
    const int lr = l & 15, lg = l >> 4;
    const int ig = i0 + w;

    float4 m1r[8];
#pragma unroll
    for (int kt = 0; kt < 4; ++kt) {
        const float* p = m1T + n * 8192 + ig * 128 + kt * 32 + lg * 8;
        m1r[kt * 2 + 0] = *(const float4*)p;
        m1r[kt * 2 + 1] = *(const float4*)(p + 4);
    }

    short* adjb = adjm + ((size_t)n << 18) + (ig << 6);

#pragma unroll 1
    for (int jt = 0; jt < 4; ++jt) {
        const float* m2row = m2s + (jt * 16 + lr) * 132;
        bf16x8 bfr[4];
#pragma unroll
        for (int kt = 0; kt < 4; ++kt) {
            const int k0 = kt * 32 + lg * 8;
            float4 b0 = *(const float4*)(m2row + k0);
            float4 b1 = *(const float4*)(m2row + k0 + 4);
            float4 a0 = m1r[kt * 2], a1 = m1r[kt * 2 + 1];
            bfr[kt][0] = f2bf(tanh_fast(a0.x - b0.x));
            bfr[kt][1] = f2bf(tanh_fast(a0.y - b0.y));
            bfr[kt][2] = f2bf(tanh_fast(a0.z - b0.z));
            bfr[kt][3] = f2bf(tanh_fast(a0.w - b0.w));
            bfr[kt][4] = f2bf(tanh_fast(a1.x - b1.x));
            bfr[kt][5] = f2bf(tanh_fast(a1.y - b1.y));
            bfr[kt][6] = f2bf(tanh_fast(a1.z - b1.z));
            bfr[kt][7] = f2bf(tanh_fast(a1.w - b1.w));
        }

        const int j0 = jt * 16 + lg * 4;
#pragma unroll
        for (int q = 0; q < 4; ++q) {
            const int tq = q * 16 + lr;
            bf16x8 af[4];
#pragma unroll
            for (int kt = 0; kt < 4; ++kt)
                af[kt] = *(const bf16x8*)(wrs + tq * 136 + kt * 32 + lg * 8);
            f32x4 acc = (f32x4){0.f, 0.f, 0.f, 0.f};
#pragma unroll
            for (int kt = 0; kt < 4; ++kt)
                acc = MFMA16(bfr[kt], af[kt], acc);             // D[j][t]
            bf16x4 pv;
            pv[0] = f2bf(acc[0]);
            pv[1] = f2bf(acc[1]);
            pv[2] = f2bf(acc[2]);
            pv[3] = f2bf(acc[3]);
            *(bf16x4*)(adjb + ((size_t)tq << 12) + j0) = pv;    // 8B store
        }
    }
}

// ---------------------------------------------------------------------------
// K2: block = one (n,t), 4 waves.  STAGED: adjs = adjm + A[t] + a*b_rm in
//   LDS via coalesced pass (no gathers); xT group-padded.  Then
//   P = adj @ x (ones-col -> rowsum), out = W_aug @ P + b_f column.
// ---------------------------------------------------------------------------
__global__ __launch_bounds__(256) void k2_out(
    const short* __restrict__ adjm, const short* __restrict__ xbf,
    const float* __restrict__ Ast,  const float* __restrict__ b_rm,
    const int* __restrict__ alpha_p,
    const float* __restrict__ w_f,  const float* __restrict__ b_f,
    float* __restrict__ out)
{
    __shared__ short adjs[64 * 72];     // [i][j] ready-adj bf16      (9.2 KB)
    __shared__ short xT[64 * 72 + 32];  // [c][j], off c*72+(c>>4)*8  (9.3 KB)
    __shared__ short P[64 * 104];       // [i][c]                    (13.3 KB)

    const int pair = blockIdx.x;        // n*64 + t
    const int t    = pair & 63;
    const int tid  = threadIdx.x;
    const int l = tid & 63, w = tid >> 6;
    const int lr = l & 15, lg = l >> 4;

    const short* Ab = adjm + ((size_t)pair << 12);
    const short* Xb = xbf  + ((size_t)pair << 12);
    const float* At = Ast  + ((size_t)t << 12);
    float*       Ob = out  + ((size_t)pair << 12);

    const float ab = alpha_decode(alpha_p) * b_rm[t];

    // ---- stage adjs = adjm + A[t] + ab  (fully coalesced reads + writes)
#pragma unroll
    for (int pass = 0; pass < 2; ++pass) {
        const int it  = pass * 256 + tid;        // 0..511
        const int row = it >> 3;
        const int c8  = (it & 7) * 8;
        bf16x8 s  = *(const bf16x8*)(Ab + row * 64 + c8);
        float4 a0 = *(const float4*)(At + row * 64 + c8);
        float4 a1 = *(const float4*)(At + row * 64 + c8 + 4);
        bf16x8 r;
        r[0] = f2bf(bf2f(s[0]) + a0.x + ab);
        r[1] = f2bf(bf2f(s[1]) + a0.y + ab);
        r[2] = f2bf(bf2f(s[2]) + a0.z + ab);
        r[3] = f2bf(bf2f(s[3]) + a0.w + ab);
        r[4] = f2bf(bf2f(s[4]) + a1.x + ab);
        r[5] = f2bf(bf2f(s[5]) + a1.y + ab);
        r[6] = f2bf(bf2f(s[6]) + a1.z + ab);
        r[7] = f2bf(bf2f(s[7]) + a1.w + ab);
        *(bf16x8*)(adjs + row * 72 + c8) = r;    // 16B/lane, conflict-free
    }

    // ---- stage xT[c][j] from xbf[j][c], group-padded layout
    {
        const int j  = tid >> 2;
        const int c0 = (tid & 3) * 16;
        bf16x8 r0 = *(const bf16x8*)(Xb + j * 64 + c0);
        bf16x8 r1 = *(const bf16x8*)(Xb + j * 64 + c0 + 8);
        const int g0 = (c0 >> 4) * 8;            // group pad
#pragma unroll
        for (int d = 0; d < 8; ++d) {
            xT[(c0 + d) * 72 + g0 + j]     = r0[d];
            xT[(c0 + 8 + d) * 72 + g0 + j] = r1[d];
        }
    }
    if (tid < 128) {
        int row = tid >> 1, cz = 80 + (tid & 1) * 8;
        bf16x8 z = {0, 0, 0, 0, 0, 0, 0, 0};
        *(bf16x8*)(P + row * 104 + cz) = z;
    }
    __syncthreads();

    // ---- hoist adj fragments from LDS (2-way banks, free)
    bf16x8 adjA[4][2];
#pragma unroll
    for (int mt = 0; mt < 4; ++mt)
#pragma unroll
        for (int ks = 0; ks < 2; ++ks)
            adjA[mt][ks] = *(const bf16x8*)(adjs + (mt * 16 + lr) * 72
                                            + ks * 32 + lg * 8);

    // ---- Phase 1: P = adj @ x  (wave w -> c-tile w); wave 0 adds ones-col
    {
        bf16x8 bx[2];
#pragma unroll
        for (int ks = 0; ks < 2; ++ks)
            bx[ks] = *(const bf16x8*)(xT + (w * 16 + lr) * 72 + w * 8
                                      + ks * 32 + lg * 8);

        f32x4 acc[4];
#pragma unroll
        for (int mt = 0; mt < 4; ++mt) acc[mt] = (f32x4){0.f, 0.f, 0.f, 0.f};
#pragma unroll
        for (int ks = 0; ks < 2; ++ks)
#pragma unroll
            for (int mt = 0; mt < 4; ++mt)
                acc[mt] = MFMA16(adjA[mt][ks], bx[ks], acc[mt]);   // D[i][c]

#pragma unroll
        for (int mt = 0; mt < 4; ++mt)
#pragma unroll
            for (int e = 0; e < 4; ++e)
                P[(mt * 16 + lg * 4 + e) * 104 + w * 16 + lr] = f2bf(acc[mt][e]);

        if (w == 0) {
            bf16x8 ones = {0, 0, 0, 0, 0, 0, 0, 0};
            if (lr == 0) {
#pragma unroll
                for (int d = 0; d < 8; ++d) ones[d] = (short)0x3F80;
            }
            f32x4 accO[4];
#pragma unroll
            for (int mt = 0; mt < 4; ++mt) accO[mt] = (f32x4){0.f, 0.f, 0.f, 0.f};
#pragma unroll
            for (int ks = 0; ks < 2; ++ks)
#pragma unroll
                for (int mt = 0; mt < 4; ++mt)
                    accO[mt] = MFMA16(adjA[mt][ks], ones, accO[mt]);
#pragma unroll
            for (int mt = 0; mt < 4; ++mt)
#pragma unroll
                for (int e = 0; e < 4; ++e)
                    P[(mt * 16 + lg * 4 + e) * 104 + 64 + lr] = f2bf(accO[mt][e]);
        }
    }
    __syncthreads();

    // ---- Phase 2: out = W_aug @ P  (wave w -> o-tile w)
    {
        const int o = w * 16 + lr;
        bf16x8 afw[3];
#pragma unroll
        for (int ks = 0; ks < 2; ++ks)
            afw[ks] = cvt8(w_f + o * 64 + ks * 32 + lg * 8);
        {
            bf16x8 ab2 = {0, 0, 0, 0, 0, 0, 0, 0};
            if (lg == 0) ab2[0] = f2bf(b_f[o]);
            afw[2] = ab2;
        }

#pragma unroll
        for (int nt = 0; nt < 4; ++nt) {
            const int i = nt * 16 + lr;
            bf16x8 bP[3];
#pragma unroll
            for (int ks = 0; ks < 3; ++ks)
                bP[ks] = *(const bf16x8*)(P + i * 104 + ks * 32 + lg * 8);
            f32x4 acc = (f32x4){0.f, 0.f, 0.f, 0.f};
#pragma unroll
            for (int ks = 0; ks < 3; ++ks)
                acc = MFMA16(afw[ks], bP[ks], acc);             // D[o][i]
            *(f32x4*)(Ob + i * 64 + w * 16 + lg * 4) = acc;
        }
    }
}

// ---------------------------------------------------------------------------
extern "C" void kernel_launch(void* const* d_in, const int* in_sizes, int n_in,
                              void* d_out, int out_size, void* d_ws, size_t ws_size,
                              hipStream_t stream)
{
    const float* x    = (const float*)d_in[0];
    const float* A    = (const float*)d_in[1];
    const float* w_m1 = (const float*)d_in[2];
    const float* b_m1 = (const float*)d_in[3];
    const float* w_m2 = (const float*)d_in[4];
    const float* b_m2 = (const float*)d_in[5];
    const float* w_rm = (const float*)d_in[6];
    const float* b_rm = (const float*)d_in[7];
    const float* w_f  = (const float*)d_in[8];
    const float* b_f  = (const float*)d_in[9];
    const int*   alpha = (const int*)d_in[10];

    // ws overlay: m1g/m2g dead after k0b; adjm reuses [0,33.5MB).
    char* ws = (char*)d_ws;
    float* m1g = (float*)(ws);
    float* m2g = (float*)(ws + (size_t)2 * 1024 * 1024);
    short* adjm = (short*)(ws);
    short* xbf = (short*)(ws + (size_t)34 * 1024 * 1024);
    float* m1T = (float*)(ws + (size_t)66 * 1024 * 1024);
    float* m2T = (float*)(ws + (size_t)68 * 1024 * 1024);
    float* out = (float*)d_out;

    k0_stream<<<dim3(8192), dim3(256), 0, stream>>>(x, w_m1, b_m1, w_m2, b_m2,
                                                    xbf, m1g, m2g);
    k0b_T<<<dim3(1024), dim3(256), 0, stream>>>(m1g, m2g, m1T, m2T);
    k1_adj<<<dim3(512), dim3(512), 0, stream>>>(w_rm, m1T, m2T, alpha, adjm);
    k2_out<<<dim3(4096), dim3(256), 0, stream>>>(adjm, xbf, A, b_rm, alpha,
                                                 w_f, b_f, out);
}

// Round 15
// 71.212 us; speedup vs baseline: 1.4776x; 1.0431x over previous
//
#include <hip/hip_runtime.h>
#include <hip/hip_bf16.h>

// ---------------------------------------------------------------------------
// DSTDGC R15.
// R14 structure (74.3 us) + native bf16 conversion everywhere: hand-rolled
// RNE f2bf was ~4 VALU/element; __float2bfloat16 lets the compiler emit
// v_cvt_pk_bf16_f32 (2 elem/inst).  k1 was the VALU-heaviest kernel (~40%
// of its VALU was conversion).  Also wrs stride 136->132 (bank spread).
// ---------------------------------------------------------------------------

typedef float  f32x4  __attribute__((ext_vector_type(4)));
typedef short  bf16x8 __attribute__((ext_vector_type(8)));
typedef short  bf16x4 __attribute__((ext_vector_type(4)));

static __device__ __forceinline__ short f2bf(float f) {
    __hip_bfloat16 h = __float2bfloat16(f);     // RNE; compiler packs pairs
    return *reinterpret_cast<short*>(&h);
}

static __device__ __forceinline__ float bf2f(short s) {
    return __uint_as_float(((unsigned)(unsigned short)s) << 16);
}

static __device__ __forceinline__ bf16x8 cvt8f(const float4 a, const float4 b) {
    bf16x8 r;
    r[0] = f2bf(a.x); r[1] = f2bf(a.y); r[2] = f2bf(a.z); r[3] = f2bf(a.w);
    r[4] = f2bf(b.x); r[5] = f2bf(b.y); r[6] = f2bf(b.z); r[7] = f2bf(b.w);
    return r;
}

static __device__ __forceinline__ bf16x8 cvt8(const float* p) {
    return cvt8f(*(const float4*)p, *(const float4*)(p + 4));
}

// tanh(x) = 1 - 2/(exp(2x)+1)
static __device__ __forceinline__ float tanh_fast(float x) {
    float e = __expf(2.0f * x);
    return 1.0f - 2.0f * __builtin_amdgcn_rcpf(e + 1.0f);
}

static __device__ __forceinline__ float dot4(float4 a, float4 b) {
    return a.x * b.x + a.y * b.y + a.z * b.z + a.w * b.w;
}

static __device__ __forceinline__ float alpha_decode(const int* p) {
    int raw = p[0];
    unsigned ur = (unsigned)(raw < 0 ? -raw : raw);
    return (ur < (1u << 23)) ? (float)raw : __int_as_float(raw);
}

#define MFMA16(a, b, c) __builtin_amdgcn_mfma_f32_16x16x32_bf16((a), (b), (c), 0, 0, 0)

// ---------------------------------------------------------------------------
// K0_stream: 8 threads per row (n,t,v).  Coalesced 16B in/out, no LDS.
// ---------------------------------------------------------------------------
__global__ __launch_bounds__(256) void k0_stream(
    const float* __restrict__ x,
    const float* __restrict__ w_m1, const float* __restrict__ b_m1,
    const float* __restrict__ w_m2, const float* __restrict__ b_m2,
    short* __restrict__ xbf, float* __restrict__ m1g, float* __restrict__ m2g)
{
    const int g  = blockIdx.x * 256 + threadIdx.x;
    const int R  = g >> 3;
    const int l8 = g & 7;
    const int c0 = l8 * 8;
    const int n  = R >> 12, tt = (R >> 6) & 63, v = R & 63;

    const float* xp = x + ((size_t)R << 6) + c0;
    const float4 a0 = *(const float4*)xp;
    const float4 a1 = *(const float4*)(xp + 4);

    float s0 = dot4(a0, *(const float4*)(w_m1 + c0))
             + dot4(a1, *(const float4*)(w_m1 + c0 + 4));
    float s1 = dot4(a0, *(const float4*)(w_m1 + 64 + c0))
             + dot4(a1, *(const float4*)(w_m1 + 64 + c0 + 4));
    float s2 = dot4(a0, *(const float4*)(w_m2 + c0))
             + dot4(a1, *(const float4*)(w_m2 + c0 + 4));
    float s3 = dot4(a0, *(const float4*)(w_m2 + 64 + c0))
             + dot4(a1, *(const float4*)(w_m2 + 64 + c0 + 4));

    *(bf16x8*)(xbf + ((size_t)R << 6) + c0) = cvt8f(a0, a1);

#pragma unroll
    for (int m = 1; m < 8; m <<= 1) {
        s0 += __shfl_xor(s0, m);
        s1 += __shfl_xor(s1, m);
        s2 += __shfl_xor(s2, m);
        s3 += __shfl_xor(s3, m);
    }
    if (l8 < 4) {
        float s    = (l8 == 0) ? s0 : (l8 == 1) ? s1 : (l8 == 2) ? s2 : s3;
        float bias = (l8 < 2) ? b_m1[l8] : b_m2[l8 - 2];
        float* base = (l8 < 2) ? m1g : m2g;
        base[n * 8192 + ((l8 & 1) * 64 + tt) * 64 + v] = s + bias;
    }
}

// ---------------------------------------------------------------------------
// K0b: transpose m1g/m2g [n][k][v] -> m1T/m2T [n][v][k].
// ---------------------------------------------------------------------------
__global__ __launch_bounds__(256) void k0b_T(
    const float* __restrict__ m1g, const float* __restrict__ m2g,
    float* __restrict__ m1T, float* __restrict__ m2T)
{
    const int idx   = blockIdx.x * 256 + threadIdx.x;
    const int which = idx >> 17;
    const int r     = idx & 131071;
    const int n     = r >> 11;
    const int rr    = r & 2047;
    const int v     = rr >> 5;
    const int k0    = (rr & 31) * 4;

    const float* s = (which ? m2g : m1g) + n * 8192 + v;
    float4 o;
    o.x = s[(k0 + 0) * 64];
    o.y = s[(k0 + 1) * 64];
    o.z = s[(k0 + 2) * 64];
    o.w = s[(k0 + 3) * 64];
    float* d = (which ? m2T : m1T) + n * 8192 + v * 128 + k0;
    *(float4*)d = o;
}

// ---------------------------------------------------------------------------
// K1: block (n, i-chunk of 8), 512 thr, grid 512.
//   adjm[n][t][i][j] = alpha * sum_k w_rm[t,k] tanh(m1[i,k]-m2[j,k])  (bf16)
// ---------------------------------------------------------------------------
__global__ __launch_bounds__(512) void k1_adj(
    const float* __restrict__ w_rm,
    const float* __restrict__ m1T,  const float* __restrict__ m2T,
    const int* __restrict__ alpha_p,
    short* __restrict__ adjm)
{
    __shared__ float m2s[64 * 132];     // [j][k] f32 stride 132     (33.8 KB)
    __shared__ short wrs[64 * 132];     // [t][k] bf16*alpha, s=132  (16.9 KB)

    const int b   = blockIdx.x;
    const int n   = b >> 3;
    const int i0  = (b & 7) * 8;
    const int tid = threadIdx.x;

    const float alpha = alpha_decode(alpha_p);

    {
        const float4* src = (const float4*)(m2T + n * 8192);
        for (int it = tid; it < 2048; it += 512) {
            int j = it >> 5, q = it & 31;
            *(float4*)(m2s + j * 132 + q * 4) = src[it];
        }
    }
    {
        const float4* src = (const float4*)w_rm;
        for (int it = tid; it < 2048; it += 512) {
            int t = it >> 5, q = it & 31;
            float4 v = src[it];
            bf16x4 pv;
            pv[0] = f2bf(alpha * v.x);
            pv[1] = f2bf(alpha * v.y);
            pv[2] = f2bf(alpha * v.z);
            pv[3] = f2bf(alpha * v.w);
            *(bf16x4*)(wrs + t * 132 + q * 4) = pv;
        }
    }
    __syncthreads();

    const int l = tid & 63, w = tid >> 6;
    const int lr = l & 15, lg = l >> 4;
    const int ig = i0 + w;

    float4 m1r[8];
#pragma unroll
    for (int kt = 0; kt < 4; ++kt) {
        const float* p = m1T + n * 8192 + ig * 128 + kt * 32 + lg * 8;
        m1r[kt * 2 + 0] = *(const float4*)p;
        m1r[kt * 2 + 1] = *(const float4*)(p + 4);
    }

    short* adjb = adjm + ((size_t)n << 18) + (ig << 6);

#pragma unroll 1
    for (int jt = 0; jt < 4; ++jt) {
        const float* m2row = m2s + (jt * 16 + lr) * 132;
        bf16x8 bfr[4];
#pragma unroll
        for (int kt = 0; kt < 4; ++kt) {
            const int k0 = kt * 32 + lg * 8;
            float4 b0 = *(const float4*)(m2row + k0);
            float4 b1 = *(const float4*)(m2row + k0 + 4);
            float4 a0 = m1r[kt * 2], a1 = m1r[kt * 2 + 1];
            bfr[kt][0] = f2bf(tanh_fast(a0.x - b0.x));
            bfr[kt][1] = f2bf(tanh_fast(a0.y - b0.y));
            bfr[kt][2] = f2bf(tanh_fast(a0.z - b0.z));
            bfr[kt][3] = f2bf(tanh_fast(a0.w - b0.w));
            bfr[kt][4] = f2bf(tanh_fast(a1.x - b1.x));
            bfr[kt][5] = f2bf(tanh_fast(a1.y - b1.y));
            bfr[kt][6] = f2bf(tanh_fast(a1.z - b1.z));
            bfr[kt][7] = f2bf(tanh_fast(a1.w - b1.w));
        }

        const int j0 = jt * 16 + lg * 4;
#pragma unroll
        for (int q = 0; q < 4; ++q) {
            const int tq = q * 16 + lr;
            bf16x8 af[4];
#pragma unroll
            for (int kt = 0; kt < 4; ++kt)
                af[kt] = *(const bf16x8*)(wrs + tq * 132 + kt * 32 + lg * 8);
            f32x4 acc = (f32x4){0.f, 0.f, 0.f, 0.f};
#pragma unroll
            for (int kt = 0; kt < 4; ++kt)
                acc = MFMA16(bfr[kt], af[kt], acc);             // D[j][t]
            bf16x4 pv;
            pv[0] = f2bf(acc[0]);
            pv[1] = f2bf(acc[1]);
            pv[2] = f2bf(acc[2]);
            pv[3] = f2bf(acc[3]);
            *(bf16x4*)(adjb + ((size_t)tq << 12) + j0) = pv;    // 8B store
        }
    }
}

// ---------------------------------------------------------------------------
// K2: block = one (n,t), 4 waves.  Coalesced LDS staging fused with
//   adj = adjm + A[t] + a*b_rm (no gathers); xT group-padded.  Then
//   P = adj @ x (ones-col -> rowsum), out = W_aug @ P + b_f column.
// ---------------------------------------------------------------------------
__global__ __launch_bounds__(256) void k2_out(
    const short* __restrict__ adjm, const short* __restrict__ xbf,
    const float* __restrict__ Ast,  const float* __restrict__ b_rm,
    const int* __restrict__ alpha_p,
    const float* __restrict__ w_f,  const float* __restrict__ b_f,
    float* __restrict__ out)
{
    __shared__ short adjs[64 * 72];     // [i][j] ready-adj bf16      (9.2 KB)
    __shared__ short xT[64 * 72 + 32];  // [c][j], off c*72+(c>>4)*8  (9.3 KB)
    __shared__ short P[64 * 104];       // [i][c]                    (13.3 KB)

    const int pair = blockIdx.x;        // n*64 + t
    const int t    = pair & 63;
    const int tid  = threadIdx.x;
    const int l = tid & 63, w = tid >> 6;
    const int lr = l & 15, lg = l >> 4;

    const short* Ab = adjm + ((size_t)pair << 12);
    const short* Xb = xbf  + ((size_t)pair << 12);
    const float* At = Ast  + ((size_t)t << 12);
    float*       Ob = out  + ((size_t)pair << 12);

    const float ab = alpha_decode(alpha_p) * b_rm[t];

    // ---- stage adjs = adjm + A[t] + ab  (fully coalesced reads + writes)
#pragma unroll
    for (int pass = 0; pass < 2; ++pass) {
        const int it  = pass * 256 + tid;        // 0..511
        const int row = it >> 3;
        const int c8  = (it & 7) * 8;
        bf16x8 s  = *(const bf16x8*)(Ab + row * 64 + c8);
        float4 a0 = *(const float4*)(At + row * 64 + c8);
        float4 a1 = *(const float4*)(At + row * 64 + c8 + 4);
        bf16x8 r;
        r[0] = f2bf(bf2f(s[0]) + a0.x + ab);
        r[1] = f2bf(bf2f(s[1]) + a0.y + ab);
        r[2] = f2bf(bf2f(s[2]) + a0.z + ab);
        r[3] = f2bf(bf2f(s[3]) + a0.w + ab);
        r[4] = f2bf(bf2f(s[4]) + a1.x + ab);
        r[5] = f2bf(bf2f(s[5]) + a1.y + ab);
        r[6] = f2bf(bf2f(s[6]) + a1.z + ab);
        r[7] = f2bf(bf2f(s[7]) + a1.w + ab);
        *(bf16x8*)(adjs + row * 72 + c8) = r;    // 16B/lane, conflict-free
    }

    // ---- stage xT[c][j] from xbf[j][c], group-padded layout
    {
        const int j  = tid >> 2;
        const int c0 = (tid & 3) * 16;
        bf16x8 r0 = *(const bf16x8*)(Xb + j * 64 + c0);
        bf16x8 r1 = *(const bf16x8*)(Xb + j * 64 + c0 + 8);
        const int g0 = (c0 >> 4) * 8;            // group pad
#pragma unroll
        for (int d = 0; d < 8; ++d) {
            xT[(c0 + d) * 72 + g0 + j]     = r0[d];
            xT[(c0 + 8 + d) * 72 + g0 + j] = r1[d];
        }
    }
    if (tid < 128) {
        int row = tid >> 1, cz = 80 + (tid & 1) * 8;
        bf16x8 z = {0, 0, 0, 0, 0, 0, 0, 0};
        *(bf16x8*)(P + row * 104 + cz) = z;
    }
    __syncthreads();

    // ---- hoist adj fragments from LDS (2-way banks, free)
    bf16x8 adjA[4][2];
#pragma unroll
    for (int mt = 0; mt < 4; ++mt)
#pragma unroll
        for (int ks = 0; ks < 2; ++ks)
            adjA[mt][ks] = *(const bf16x8*)(adjs + (mt * 16 + lr) * 72
                                            + ks * 32 + lg * 8);

    // ---- Phase 1: P = adj @ x  (wave w -> c-tile w); wave 0 adds ones-col
    {
        bf16x8 bx[2];
#pragma unroll
        for (int ks = 0; ks < 2; ++ks)
            bx[ks] = *(const bf16x8*)(xT + (w * 16 + lr) * 72 + w * 8
                                      + ks * 32 + lg * 8);

        f32x4 acc[4];
#pragma unroll
        for (int mt = 0; mt < 4; ++mt) acc[mt] = (f32x4){0.f, 0.f, 0.f, 0.f};
#pragma unroll
        for (int ks = 0; ks < 2; ++ks)
#pragma unroll
            for (int mt = 0; mt < 4; ++mt)
                acc[mt] = MFMA16(adjA[mt][ks], bx[ks], acc[mt]);   // D[i][c]

#pragma unroll
        for (int mt = 0; mt < 4; ++mt)
#pragma unroll
            for (int e = 0; e < 4; ++e)
                P[(mt * 16 + lg * 4 + e) * 104 + w * 16 + lr] = f2bf(acc[mt][e]);

        if (w == 0) {
            bf16x8 ones = {0, 0, 0, 0, 0, 0, 0, 0};
            if (lr == 0) {
#pragma unroll
                for (int d = 0; d < 8; ++d) ones[d] = (short)0x3F80;
            }
            f32x4 accO[4];
#pragma unroll
            for (int mt = 0; mt < 4; ++mt) accO[mt] = (f32x4){0.f, 0.f, 0.f, 0.f};
#pragma unroll
            for (int ks = 0; ks < 2; ++ks)
#pragma unroll
                for (int mt = 0; mt < 4; ++mt)
                    accO[mt] = MFMA16(adjA[mt][ks], ones, accO[mt]);
#pragma unroll
            for (int mt = 0; mt < 4; ++mt)
#pragma unroll
                for (int e = 0; e < 4; ++e)
                    P[(mt * 16 + lg * 4 + e) * 104 + 64 + lr] = f2bf(accO[mt][e]);
        }
    }
    __syncthreads();

    // ---- Phase 2: out = W_aug @ P  (wave w -> o-tile w)
    {
        const int o = w * 16 + lr;
        bf16x8 afw[3];
#pragma unroll
        for (int ks = 0; ks < 2; ++ks)
            afw[ks] = cvt8(w_f + o * 64 + ks * 32 + lg * 8);
        {
            bf16x8 ab2 = {0, 0, 0, 0, 0, 0, 0, 0};
            if (lg == 0) ab2[0] = f2bf(b_f[o]);
            afw[2] = ab2;
        }

#pragma unroll
        for (int nt = 0; nt < 4; ++nt) {
            const int i = nt * 16 + lr;
            bf16x8 bP[3];
#pragma unroll
            for (int ks = 0; ks < 3; ++ks)
                bP[ks] = *(const bf16x8*)(P + i * 104 + ks * 32 + lg * 8);
            f32x4 acc = (f32x4){0.f, 0.f, 0.f, 0.f};
#pragma unroll
            for (int ks = 0; ks < 3; ++ks)
                acc = MFMA16(afw[ks], bP[ks], acc);             // D[o][i]
            *(f32x4*)(Ob + i * 64 + w * 16 + lg * 4) = acc;
        }
    }
}

// ---------------------------------------------------------------------------
extern "C" void kernel_launch(void* const* d_in, const int* in_sizes, int n_in,
                              void* d_out, int out_size, void* d_ws, size_t ws_size,
                              hipStream_t stream)
{
    const float* x    = (const float*)d_in[0];
    const float* A    = (const float*)d_in[1];
    const float* w_m1 = (const float*)d_in[2];
    const float* b_m1 = (const float*)d_in[3];
    const float* w_m2 = (const float*)d_in[4];
    const float* b_m2 = (const float*)d_in[5];
    const float* w_rm = (const float*)d_in[6];
    const float* b_rm = (const float*)d_in[7];
    const float* w_f  = (const float*)d_in[8];
    const float* b_f  = (const float*)d_in[9];
    const int*   alpha = (const int*)d_in[10];

    // ws overlay: m1g/m2g dead after k0b; adjm reuses [0,33.5MB).
    char* ws = (char*)d_ws;
    float* m1g = (float*)(ws);
    float* m2g = (float*)(ws + (size_t)2 * 1024 * 1024);
    short* adjm = (short*)(ws);
    short* xbf = (short*)(ws + (size_t)34 * 1024 * 1024);
    float* m1T = (float*)(ws + (size_t)66 * 1024 * 1024);
    float* m2T = (float*)(ws + (size_t)68 * 1024 * 1024);
    float* out = (float*)d_out;

    k0_stream<<<dim3(8192), dim3(256), 0, stream>>>(x, w_m1, b_m1, w_m2, b_m2,
                                                    xbf, m1g, m2g);
    k0b_T<<<dim3(1024), dim3(256), 0, stream>>>(m1g, m2g, m1T, m2T);
    k1_adj<<<dim3(512), dim3(512), 0, stream>>>(w_rm, m1T, m2T, alpha, adjm);
    k2_out<<<dim3(4096), dim3(256), 0, stream>>>(adjm, xbf, A, b_rm, alpha,
                                                 w_f, b_f, out);
}

// Round 16
// 70.468 us; speedup vs baseline: 1.4932x; 1.0106x over previous
//
#include <hip/hip_runtime.h>
#include <hip/hip_bf16.h>

// ---------------------------------------------------------------------------
// DSTDGC R16.
// k0_stream2: block = (n, v-chunk of 8), 512 thr.  Loops all t; computes
//   xbf copy + m projections; accumulates msT in LDS (no in-loop barrier);
//   final pass writes m1T/m2T[n][v][k] DIRECTLY (k0b eliminated).
// k1 / k2: byte-identical to R15 (71.2 us, proven).
// ---------------------------------------------------------------------------

typedef float  f32x4  __attribute__((ext_vector_type(4)));
typedef short  bf16x8 __attribute__((ext_vector_type(8)));
typedef short  bf16x4 __attribute__((ext_vector_type(4)));

static __device__ __forceinline__ short f2bf(float f) {
    __hip_bfloat16 h = __float2bfloat16(f);     // RNE; compiler packs pairs
    return *reinterpret_cast<short*>(&h);
}

static __device__ __forceinline__ float bf2f(short s) {
    return __uint_as_float(((unsigned)(unsigned short)s) << 16);
}

static __device__ __forceinline__ bf16x8 cvt8f(const float4 a, const float4 b) {
    bf16x8 r;
    r[0] = f2bf(a.x); r[1] = f2bf(a.y); r[2] = f2bf(a.z); r[3] = f2bf(a.w);
    r[4] = f2bf(b.x); r[5] = f2bf(b.y); r[6] = f2bf(b.z); r[7] = f2bf(b.w);
    return r;
}

static __device__ __forceinline__ bf16x8 cvt8(const float* p) {
    return cvt8f(*(const float4*)p, *(const float4*)(p + 4));
}

// tanh(x) = 1 - 2/(exp(2x)+1)
static __device__ __forceinline__ float tanh_fast(float x) {
    float e = __expf(2.0f * x);
    return 1.0f - 2.0f * __builtin_amdgcn_rcpf(e + 1.0f);
}

static __device__ __forceinline__ float dot4(float4 a, float4 b) {
    return a.x * b.x + a.y * b.y + a.z * b.z + a.w * b.w;
}

static __device__ __forceinline__ float alpha_decode(const int* p) {
    int raw = p[0];
    unsigned ur = (unsigned)(raw < 0 ? -raw : raw);
    return (ur < (1u << 23)) ? (float)raw : __int_as_float(raw);
}

#define MFMA16(a, b, c) __builtin_amdgcn_mfma_f32_16x16x32_bf16((a), (b), (c), 0, 0, 0)

// ---------------------------------------------------------------------------
// K0_stream2: block b = n*8 + vc (v0 = vc*8), 512 threads.
//   thread: tl = tid>>6 (t-lane), vv = (tid>>3)&7, cg = tid&7 (c0 = cg*8).
//   Iter it: t = it*8 + tl.  Reads x (2KB/wave contiguous), writes xbf
//   (1KB/wave contiguous), dots -> shfl(8) -> msT[sel][vv][t] (disjoint t).
//   Final: coalesced float4 writes of m1T/m2T[n][v][k], k = r*64 + t.
// ---------------------------------------------------------------------------
__global__ __launch_bounds__(512) void k0_stream2(
    const float* __restrict__ x,
    const float* __restrict__ w_m1, const float* __restrict__ b_m1,
    const float* __restrict__ w_m2, const float* __restrict__ b_m2,
    short* __restrict__ xbf, float* __restrict__ m1T, float* __restrict__ m2T)
{
    __shared__ float msT[4][8][68];     // [sel][vv][t], stride 68 (f4-aligned)

    const int b   = blockIdx.x;         // n*8 + vc
    const int n   = b >> 3;
    const int v0  = (b & 7) * 8;
    const int tid = threadIdx.x;
    const int tl  = tid >> 6;           // 0..7
    const int vv  = (tid >> 3) & 7;     // 0..7
    const int cg  = tid & 7;            // 0..7
    const int c0  = cg * 8;

    // hoisted weight rows (L2-hot broadcasts)
    const float4 w10 = *(const float4*)(w_m1 + c0);
    const float4 w11 = *(const float4*)(w_m1 + c0 + 4);
    const float4 w20 = *(const float4*)(w_m1 + 64 + c0);
    const float4 w21 = *(const float4*)(w_m1 + 64 + c0 + 4);
    const float4 w30 = *(const float4*)(w_m2 + c0);
    const float4 w31 = *(const float4*)(w_m2 + c0 + 4);
    const float4 w40 = *(const float4*)(w_m2 + 64 + c0);
    const float4 w41 = *(const float4*)(w_m2 + 64 + c0 + 4);

#pragma unroll 2
    for (int it = 0; it < 8; ++it) {
        const int t = it * 8 + tl;
        const size_t R = ((size_t)(n * 64 + t)) * 64 + (v0 + vv);
        const float* xp = x + (R << 6) + c0;
        const float4 a0 = *(const float4*)xp;
        const float4 a1 = *(const float4*)(xp + 4);

        float s0 = dot4(a0, w10) + dot4(a1, w11);
        float s1 = dot4(a0, w20) + dot4(a1, w21);
        float s2 = dot4(a0, w30) + dot4(a1, w31);
        float s3 = dot4(a0, w40) + dot4(a1, w41);

        *(bf16x8*)(xbf + (R << 6) + c0) = cvt8f(a0, a1);

#pragma unroll
        for (int m = 1; m < 8; m <<= 1) {
            s0 += __shfl_xor(s0, m);
            s1 += __shfl_xor(s1, m);
            s2 += __shfl_xor(s2, m);
            s3 += __shfl_xor(s3, m);
        }
        if (cg < 4) {                   // per-t regions disjoint -> no barrier
            float s = (cg == 0) ? s0 : (cg == 1) ? s1 : (cg == 2) ? s2 : s3;
            msT[cg][vv][t] = s;
        }
    }
    __syncthreads();

    // ---- final coalesced m writes: thread -> (m, vv2, kq)
    {
        const int m   = tid >> 8;        // 0: m1, 1: m2
        const int rem = tid & 255;
        const int vv2 = rem >> 5;        // 0..7
        const int k0  = (rem & 31) * 4;  // 0..124
        const int r   = k0 >> 6;
        const int sel = m * 2 + r;
        const int t0  = k0 & 63;
        float4 val = *(const float4*)&msT[sel][vv2][t0];
        const float bias = (m == 0) ? b_m1[r] : b_m2[r];
        val.x += bias; val.y += bias; val.z += bias; val.w += bias;
        float* dst = ((m == 0) ? m1T : m2T) + n * 8192 + (v0 + vv2) * 128 + k0;
        *(float4*)dst = val;
    }
}

// ---------------------------------------------------------------------------
// K1: block (n, i-chunk of 8), 512 thr, grid 512.  (R15, unchanged)
//   adjm[n][t][i][j] = alpha * sum_k w_rm[t,k] tanh(m1[i,k]-m2[j,k])  (bf16)
// ---------------------------------------------------------------------------
__global__ __launch_bounds__(512) void k1_adj(
    const float* __restrict__ w_rm,
    const float* __restrict__ m1T,  const float* __restrict__ m2T,
    const int* __restrict__ alpha_p,
    short* __restrict__ adjm)
{
    __shared__ float m2s[64 * 132];     // [j][k] f32 stride 132     (33.8 KB)
    __shared__ short wrs[64 * 132];     // [t][k] bf16*alpha, s=132  (16.9 KB)

    const int b   = blockIdx.x;
    const int n   = b >> 3;
    const int i0  = (b & 7) * 8;
    const int tid = threadIdx.x;

    const float alpha = alpha_decode(alpha_p);

    {
        const float4* src = (const float4*)(m2T + n * 8192);
        for (int it = tid; it < 2048; it += 512) {
            int j = it >> 5, q = it & 31;
            *(float4*)(m2s + j * 132 + q * 4) = src[it];
        }
    }
    {
        const float4* src = (const float4*)w_rm;
        for (int it = tid; it < 2048; it += 512) {
            int t = it >> 5, q = it & 31;
            float4 v = src[it];
            bf16x4 pv;
            pv[0] = f2bf(alpha * v.x);
            pv[1] = f2bf(alpha * v.y);
            pv[2] = f2bf(alpha * v.z);
            pv[3] = f2bf(alpha * v.w);
            *(bf16x4*)(wrs + t * 132 + q * 4) = pv;
        }
    }
    __syncthreads();

    const int l = tid & 63, w = tid >> 6;
    const int lr = l & 15, lg = l >> 4;
    const int ig = i0 + w;

    float4 m1r[8];
#pragma unroll
    for (int kt = 0; kt < 4; ++kt) {
        const float* p = m1T + n * 8192 + ig * 128 + kt * 32 + lg * 8;
        m1r[kt * 2 + 0] = *(const float4*)p;
        m1r[kt * 2 + 1] = *(const float4*)(p + 4);
    }

    short* adjb = adjm + ((size_t)n << 18) + (ig << 6);

#pragma unroll 1
    for (int jt = 0; jt < 4; ++jt) {
        const float* m2row = m2s + (jt * 16 + lr) * 132;
        bf16x8 bfr[4];
#pragma unroll
        for (int kt = 0; kt < 4; ++kt) {
            const int k0 = kt * 32 + lg * 8;
            float4 b0 = *(const float4*)(m2row + k0);
            float4 b1 = *(const float4*)(m2row + k0 + 4);
            float4 a0 = m1r[kt * 2], a1 = m1r[kt * 2 + 1];
            bfr[kt][0] = f2bf(tanh_fast(a0.x - b0.x));
            bfr[kt][1] = f2bf(tanh_fast(a0.y - b0.y));
            bfr[kt][2] = f2bf(tanh_fast(a0.z - b0.z));
            bfr[kt][3] = f2bf(tanh_fast(a0.w - b0.w));
            bfr[kt][4] = f2bf(tanh_fast(a1.x - b1.x));
            bfr[kt][5] = f2bf(tanh_fast(a1.y - b1.y));
            bfr[kt][6] = f2bf(tanh_fast(a1.z - b1.z));
            bfr[kt][7] = f2bf(tanh_fast(a1.w - b1.w));
        }

        const int j0 = jt * 16 + lg * 4;
#pragma unroll
        for (int q = 0; q < 4; ++q) {
            const int tq = q * 16 + lr;
            bf16x8 af[4];
#pragma unroll
            for (int kt = 0; kt < 4; ++kt)
                af[kt] = *(const bf16x8*)(wrs + tq * 132 + kt * 32 + lg * 8);
            f32x4 acc = (f32x4){0.f, 0.f, 0.f, 0.f};
#pragma unroll
            for (int kt = 0; kt < 4; ++kt)
                acc = MFMA16(bfr[kt], af[kt], acc);             // D[j][t]
            bf16x4 pv;
            pv[0] = f2bf(acc[0]);
            pv[1] = f2bf(acc[1]);
            pv[2] = f2bf(acc[2]);
            pv[3] = f2bf(acc[3]);
            *(bf16x4*)(adjb + ((size_t)tq << 12) + j0) = pv;    // 8B store
        }
    }
}

// ---------------------------------------------------------------------------
// K2: block = one (n,t), 4 waves.  (R15, unchanged)
// ---------------------------------------------------------------------------
__global__ __launch_bounds__(256) void k2_out(
    const short* __restrict__ adjm, const short* __restrict__ xbf,
    const float* __restrict__ Ast,  const float* __restrict__ b_rm,
    const int* __restrict__ alpha_p,
    const float* __restrict__ w_f,  const float* __restrict__ b_f,
    float* __restrict__ out)
{
    __shared__ short adjs[64 * 72];     // [i][j] ready-adj bf16      (9.2 KB)
    __shared__ short xT[64 * 72 + 32];  // [c][j], off c*72+(c>>4)*8  (9.3 KB)
    __shared__ short P[64 * 104];       // [i][c]                    (13.3 KB)

    const int pair = blockIdx.x;        // n*64 + t
    const int t    = pair & 63;
    const int tid  = threadIdx.x;
    const int l = tid & 63, w = tid >> 6;
    const int lr = l & 15, lg = l >> 4;

    const short* Ab = adjm + ((size_t)pair << 12);
    const short* Xb = xbf  + ((size_t)pair << 12);
    const float* At = Ast  + ((size_t)t << 12);
    float*       Ob = out  + ((size_t)pair << 12);

    const float ab = alpha_decode(alpha_p) * b_rm[t];

    // ---- stage adjs = adjm + A[t] + ab  (fully coalesced reads + writes)
#pragma unroll
    for (int pass = 0; pass < 2; ++pass) {
        const int it  = pass * 256 + tid;        // 0..511
        const int row = it >> 3;
        const int c8  = (it & 7) * 8;
        bf16x8 s  = *(const bf16x8*)(Ab + row * 64 + c8);
        float4 a0 = *(const float4*)(At + row * 64 + c8);
        float4 a1 = *(const float4*)(At + row * 64 + c8 + 4);
        bf16x8 r;
        r[0] = f2bf(bf2f(s[0]) + a0.x + ab);
        r[1] = f2bf(bf2f(s[1]) + a0.y + ab);
        r[2] = f2bf(bf2f(s[2]) + a0.z + ab);
        r[3] = f2bf(bf2f(s[3]) + a0.w + ab);
        r[4] = f2bf(bf2f(s[4]) + a1.x + ab);
        r[5] = f2bf(bf2f(s[5]) + a1.y + ab);
        r[6] = f2bf(bf2f(s[6]) + a1.z + ab);
        r[7] = f2bf(bf2f(s[7]) + a1.w + ab);
        *(bf16x8*)(adjs + row * 72 + c8) = r;    // 16B/lane, conflict-free
    }

    // ---- stage xT[c][j] from xbf[j][c], group-padded layout
    {
        const int j  = tid >> 2;
        const int c0 = (tid & 3) * 16;
        bf16x8 r0 = *(const bf16x8*)(Xb + j * 64 + c0);
        bf16x8 r1 = *(const bf16x8*)(Xb + j * 64 + c0 + 8);
        const int g0 = (c0 >> 4) * 8;            // group pad
#pragma unroll
        for (int d = 0; d < 8; ++d) {
            xT[(c0 + d) * 72 + g0 + j]     = r0[d];
            xT[(c0 + 8 + d) * 72 + g0 + j] = r1[d];
        }
    }
    if (tid < 128) {
        int row = tid >> 1, cz = 80 + (tid & 1) * 8;
        bf16x8 z = {0, 0, 0, 0, 0, 0, 0, 0};
        *(bf16x8*)(P + row * 104 + cz) = z;
    }
    __syncthreads();

    // ---- hoist adj fragments from LDS (2-way banks, free)
    bf16x8 adjA[4][2];
#pragma unroll
    for (int mt = 0; mt < 4; ++mt)
#pragma unroll
        for (int ks = 0; ks < 2; ++ks)
            adjA[mt][ks] = *(const bf16x8*)(adjs + (mt * 16 + lr) * 72
                                            + ks * 32 + lg * 8);

    // ---- Phase 1: P = adj @ x  (wave w -> c-tile w); wave 0 adds ones-col
    {
        bf16x8 bx[2];
#pragma unroll
        for (int ks = 0; ks < 2; ++ks)
            bx[ks] = *(const bf16x8*)(xT + (w * 16 + lr) * 72 + w * 8
                                      + ks * 32 + lg * 8);

        f32x4 acc[4];
#pragma unroll
        for (int mt = 0; mt < 4; ++mt) acc[mt] = (f32x4){0.f, 0.f, 0.f, 0.f};
#pragma unroll
        for (int ks = 0; ks < 2; ++ks)
#pragma unroll
            for (int mt = 0; mt < 4; ++mt)
                acc[mt] = MFMA16(adjA[mt][ks], bx[ks], acc[mt]);   // D[i][c]

#pragma unroll
        for (int mt = 0; mt < 4; ++mt)
#pragma unroll
            for (int e = 0; e < 4; ++e)
                P[(mt * 16 + lg * 4 + e) * 104 + w * 16 + lr] = f2bf(acc[mt][e]);

        if (w == 0) {
            bf16x8 ones = {0, 0, 0, 0, 0, 0, 0, 0};
            if (lr == 0) {
#pragma unroll
                for (int d = 0; d < 8; ++d) ones[d] = (short)0x3F80;
            }
            f32x4 accO[4];
#pragma unroll
            for (int mt = 0; mt < 4; ++mt) accO[mt] = (f32x4){0.f, 0.f, 0.f, 0.f};
#pragma unroll
            for (int ks = 0; ks < 2; ++ks)
#pragma unroll
                for (int mt = 0; mt < 4; ++mt)
                    accO[mt] = MFMA16(adjA[mt][ks], ones, accO[mt]);
#pragma unroll
            for (int mt = 0; mt < 4; ++mt)
#pragma unroll
                for (int e = 0; e < 4; ++e)
                    P[(mt * 16 + lg * 4 + e) * 104 + 64 + lr] = f2bf(accO[mt][e]);
        }
    }
    __syncthreads();

    // ---- Phase 2: out = W_aug @ P  (wave w -> o-tile w)
    {
        const int o = w * 16 + lr;
        bf16x8 afw[3];
#pragma unroll
        for (int ks = 0; ks < 2; ++ks)
            afw[ks] = cvt8(w_f + o * 64 + ks * 32 + lg * 8);
        {
            bf16x8 ab2 = {0, 0, 0, 0, 0, 0, 0, 0};
            if (lg == 0) ab2[0] = f2bf(b_f[o]);
            afw[2] = ab2;
        }

#pragma unroll
        for (int nt = 0; nt < 4; ++nt) {
            const int i = nt * 16 + lr;
            bf16x8 bP[3];
#pragma unroll
            for (int ks = 0; ks < 3; ++ks)
                bP[ks] = *(const bf16x8*)(P + i * 104 + ks * 32 + lg * 8);
            f32x4 acc = (f32x4){0.f, 0.f, 0.f, 0.f};
#pragma unroll
            for (int ks = 0; ks < 3; ++ks)
                acc = MFMA16(afw[ks], bP[ks], acc);             // D[o][i]
            *(f32x4*)(Ob + i * 64 + w * 16 + lg * 4) = acc;
        }
    }
}

// ---------------------------------------------------------------------------
extern "C" void kernel_launch(void* const* d_in, const int* in_sizes, int n_in,
                              void* d_out, int out_size, void* d_ws, size_t ws_size,
                              hipStream_t stream)
{
    const float* x    = (const float*)d_in[0];
    const float* A    = (const float*)d_in[1];
    const float* w_m1 = (const float*)d_in[2];
    const float* b_m1 = (const float*)d_in[3];
    const float* w_m2 = (const float*)d_in[4];
    const float* b_m2 = (const float*)d_in[5];
    const float* w_rm = (const float*)d_in[6];
    const float* b_rm = (const float*)d_in[7];
    const float* w_f  = (const float*)d_in[8];
    const float* b_f  = (const float*)d_in[9];
    const int*   alpha = (const int*)d_in[10];

    // ws layout: adjm [0,33.5MB), xbf [34,66MB), m1T [66,68), m2T [68,70).
    char* ws = (char*)d_ws;
    short* adjm = (short*)(ws);
    short* xbf = (short*)(ws + (size_t)34 * 1024 * 1024);
    float* m1T = (float*)(ws + (size_t)66 * 1024 * 1024);
    float* m2T = (float*)(ws + (size_t)68 * 1024 * 1024);
    float* out = (float*)d_out;

    k0_stream2<<<dim3(512), dim3(512), 0, stream>>>(x, w_m1, b_m1, w_m2, b_m2,
                                                    xbf, m1T, m2T);
    k1_adj<<<dim3(512), dim3(512), 0, stream>>>(w_rm, m1T, m2T, alpha, adjm);
    k2_out<<<dim3(4096), dim3(256), 0, stream>>>(adjm, xbf, A, b_rm, alpha,
                                                 w_f, b_f, out);
}

// Round 17
// 68.915 us; speedup vs baseline: 1.5269x; 1.0225x over previous
//
#include <hip/hip_runtime.h>
#include <hip/hip_bf16.h>

// ---------------------------------------------------------------------------
// DSTDGC R17.
// k0_stream2 / k1_adj: unchanged from R16 (70.5 us, proven).
// k2: T14 async-STAGE split — block = 2 consecutive (n,t) pairs; pair-1's
//     global loads issued during pair-0's MFMA phases (HBM latency hidden);
//     single LDS buffer reused with barrier-separated overwrites; w_f/b_f
//     fragments hoisted once per block.
// ---------------------------------------------------------------------------

typedef float  f32x4  __attribute__((ext_vector_type(4)));
typedef short  bf16x8 __attribute__((ext_vector_type(8)));
typedef short  bf16x4 __attribute__((ext_vector_type(4)));

static __device__ __forceinline__ short f2bf(float f) {
    __hip_bfloat16 h = __float2bfloat16(f);     // RNE; compiler packs pairs
    return *reinterpret_cast<short*>(&h);
}

static __device__ __forceinline__ float bf2f(short s) {
    return __uint_as_float(((unsigned)(unsigned short)s) << 16);
}

static __device__ __forceinline__ bf16x8 cvt8f(const float4 a, const float4 b) {
    bf16x8 r;
    r[0] = f2bf(a.x); r[1] = f2bf(a.y); r[2] = f2bf(a.z); r[3] = f2bf(a.w);
    r[4] = f2bf(b.x); r[5] = f2bf(b.y); r[6] = f2bf(b.z); r[7] = f2bf(b.w);
    return r;
}

static __device__ __forceinline__ bf16x8 cvt8(const float* p) {
    return cvt8f(*(const float4*)p, *(const float4*)(p + 4));
}

// tanh(x) = 1 - 2/(exp(2x)+1)
static __device__ __forceinline__ float tanh_fast(float x) {
    float e = __expf(2.0f * x);
    return 1.0f - 2.0f * __builtin_amdgcn_rcpf(e + 1.0f);
}

static __device__ __forceinline__ float dot4(float4 a, float4 b) {
    return a.x * b.x + a.y * b.y + a.z * b.z + a.w * b.w;
}

static __device__ __forceinline__ float alpha_decode(const int* p) {
    int raw = p[0];
    unsigned ur = (unsigned)(raw < 0 ? -raw : raw);
    return (ur < (1u << 23)) ? (float)raw : __int_as_float(raw);
}

static __device__ __forceinline__ bf16x8 fuse8(bf16x8 s, float4 a0, float4 a1,
                                               float ab) {
    bf16x8 r;
    r[0] = f2bf(bf2f(s[0]) + a0.x + ab);
    r[1] = f2bf(bf2f(s[1]) + a0.y + ab);
    r[2] = f2bf(bf2f(s[2]) + a0.z + ab);
    r[3] = f2bf(bf2f(s[3]) + a0.w + ab);
    r[4] = f2bf(bf2f(s[4]) + a1.x + ab);
    r[5] = f2bf(bf2f(s[5]) + a1.y + ab);
    r[6] = f2bf(bf2f(s[6]) + a1.z + ab);
    r[7] = f2bf(bf2f(s[7]) + a1.w + ab);
    return r;
}

#define MFMA16(a, b, c) __builtin_amdgcn_mfma_f32_16x16x32_bf16((a), (b), (c), 0, 0, 0)

// ---------------------------------------------------------------------------
// K0_stream2: block b = n*8 + vc (v0 = vc*8), 512 threads.  (R16, unchanged)
// ---------------------------------------------------------------------------
__global__ __launch_bounds__(512) void k0_stream2(
    const float* __restrict__ x,
    const float* __restrict__ w_m1, const float* __restrict__ b_m1,
    const float* __restrict__ w_m2, const float* __restrict__ b_m2,
    short* __restrict__ xbf, float* __restrict__ m1T, float* __restrict__ m2T)
{
    __shared__ float msT[4][8][68];     // [sel][vv][t], stride 68 (f4-aligned)

    const int b   = blockIdx.x;         // n*8 + vc
    const int n   = b >> 3;
    const int v0  = (b & 7) * 8;
    const int tid = threadIdx.x;
    const int tl  = tid >> 6;           // 0..7
    const int vv  = (tid >> 3) & 7;     // 0..7
    const int cg  = tid & 7;            // 0..7
    const int c0  = cg * 8;

    const float4 w10 = *(const float4*)(w_m1 + c0);
    const float4 w11 = *(const float4*)(w_m1 + c0 + 4);
    const float4 w20 = *(const float4*)(w_m1 + 64 + c0);
    const float4 w21 = *(const float4*)(w_m1 + 64 + c0 + 4);
    const float4 w30 = *(const float4*)(w_m2 + c0);
    const float4 w31 = *(const float4*)(w_m2 + c0 + 4);
    const float4 w40 = *(const float4*)(w_m2 + 64 + c0);
    const float4 w41 = *(const float4*)(w_m2 + 64 + c0 + 4);

#pragma unroll 2
    for (int it = 0; it < 8; ++it) {
        const int t = it * 8 + tl;
        const size_t R = ((size_t)(n * 64 + t)) * 64 + (v0 + vv);
        const float* xp = x + (R << 6) + c0;
        const float4 a0 = *(const float4*)xp;
        const float4 a1 = *(const float4*)(xp + 4);

        float s0 = dot4(a0, w10) + dot4(a1, w11);
        float s1 = dot4(a0, w20) + dot4(a1, w21);
        float s2 = dot4(a0, w30) + dot4(a1, w31);
        float s3 = dot4(a0, w40) + dot4(a1, w41);

        *(bf16x8*)(xbf + (R << 6) + c0) = cvt8f(a0, a1);

#pragma unroll
        for (int m = 1; m < 8; m <<= 1) {
            s0 += __shfl_xor(s0, m);
            s1 += __shfl_xor(s1, m);
            s2 += __shfl_xor(s2, m);
            s3 += __shfl_xor(s3, m);
        }
        if (cg < 4) {                   // per-t regions disjoint -> no barrier
            float s = (cg == 0) ? s0 : (cg == 1) ? s1 : (cg == 2) ? s2 : s3;
            msT[cg][vv][t] = s;
        }
    }
    __syncthreads();

    {
        const int m   = tid >> 8;        // 0: m1, 1: m2
        const int rem = tid & 255;
        const int vv2 = rem >> 5;        // 0..7
        const int k0  = (rem & 31) * 4;  // 0..124
        const int r   = k0 >> 6;
        const int sel = m * 2 + r;
        const int t0  = k0 & 63;
        float4 val = *(const float4*)&msT[sel][vv2][t0];
        const float bias = (m == 0) ? b_m1[r] : b_m2[r];
        val.x += bias; val.y += bias; val.z += bias; val.w += bias;
        float* dst = ((m == 0) ? m1T : m2T) + n * 8192 + (v0 + vv2) * 128 + k0;
        *(float4*)dst = val;
    }
}

// ---------------------------------------------------------------------------
// K1: block (n, i-chunk of 8), 512 thr, grid 512.  (R16, unchanged)
// ---------------------------------------------------------------------------
__global__ __launch_bounds__(512) void k1_adj(
    const float* __restrict__ w_rm,
    const float* __restrict__ m1T,  const float* __restrict__ m2T,
    const int* __restrict__ alpha_p,
    short* __restrict__ adjm)
{
    __shared__ float m2s[64 * 132];     // [j][k] f32 stride 132     (33.8 KB)
    __shared__ short wrs[64 * 132];     // [t][k] bf16*alpha, s=132  (16.9 KB)

    const int b   = blockIdx.x;
    const int n   = b >> 3;
    const int i0  = (b & 7) * 8;
    const int tid = threadIdx.x;

    const float alpha = alpha_decode(alpha_p);

    {
        const float4* src = (const float4*)(m2T + n * 8192);
        for (int it = tid; it < 2048; it += 512) {
            int j = it >> 5, q = it & 31;
            *(float4*)(m2s + j * 132 + q * 4) = src[it];
        }
    }
    {
        const float4* src = (const float4*)w_rm;
        for (int it = tid; it < 2048; it += 512) {
            int t = it >> 5, q = it & 31;
            float4 v = src[it];
            bf16x4 pv;
            pv[0] = f2bf(alpha * v.x);
            pv[1] = f2bf(alpha * v.y);
            pv[2] = f2bf(alpha * v.z);
            pv[3] = f2bf(alpha * v.w);
            *(bf16x4*)(wrs + t * 132 + q * 4) = pv;
        }
    }
    __syncthreads();

    const int l = tid & 63, w = tid >> 6;
    const int lr = l & 15, lg = l >> 4;
    const int ig = i0 + w;

    float4 m1r[8];
#pragma unroll
    for (int kt = 0; kt < 4; ++kt) {
        const float* p = m1T + n * 8192 + ig * 128 + kt * 32 + lg * 8;
        m1r[kt * 2 + 0] = *(const float4*)p;
        m1r[kt * 2 + 1] = *(const float4*)(p + 4);
    }

    short* adjb = adjm + ((size_t)n << 18) + (ig << 6);

#pragma unroll 1
    for (int jt = 0; jt < 4; ++jt) {
        const float* m2row = m2s + (jt * 16 + lr) * 132;
        bf16x8 bfr[4];
#pragma unroll
        for (int kt = 0; kt < 4; ++kt) {
            const int k0 = kt * 32 + lg * 8;
            float4 b0 = *(const float4*)(m2row + k0);
            float4 b1 = *(const float4*)(m2row + k0 + 4);
            float4 a0 = m1r[kt * 2], a1 = m1r[kt * 2 + 1];
            bfr[kt][0] = f2bf(tanh_fast(a0.x - b0.x));
            bfr[kt][1] = f2bf(tanh_fast(a0.y - b0.y));
            bfr[kt][2] = f2bf(tanh_fast(a0.z - b0.z));
            bfr[kt][3] = f2bf(tanh_fast(a0.w - b0.w));
            bfr[kt][4] = f2bf(tanh_fast(a1.x - b1.x));
            bfr[kt][5] = f2bf(tanh_fast(a1.y - b1.y));
            bfr[kt][6] = f2bf(tanh_fast(a1.z - b1.z));
            bfr[kt][7] = f2bf(tanh_fast(a1.w - b1.w));
        }

        const int j0 = jt * 16 + lg * 4;
#pragma unroll
        for (int q = 0; q < 4; ++q) {
            const int tq = q * 16 + lr;
            bf16x8 af[4];
#pragma unroll
            for (int kt = 0; kt < 4; ++kt)
                af[kt] = *(const bf16x8*)(wrs + tq * 132 + kt * 32 + lg * 8);
            f32x4 acc = (f32x4){0.f, 0.f, 0.f, 0.f};
#pragma unroll
            for (int kt = 0; kt < 4; ++kt)
                acc = MFMA16(bfr[kt], af[kt], acc);             // D[j][t]
            bf16x4 pv;
            pv[0] = f2bf(acc[0]);
            pv[1] = f2bf(acc[1]);
            pv[2] = f2bf(acc[2]);
            pv[3] = f2bf(acc[3]);
            *(bf16x4*)(adjb + ((size_t)tq << 12) + j0) = pv;    // 8B store
        }
    }
}

// ---------------------------------------------------------------------------
// K2: block = TWO consecutive (n,t) pairs, 256 thr, grid 2048.  T14 split:
//   pair-1 loads issued during pair-0 compute.  Single LDS buffer, all
//   overwrites barrier-separated (phase2 reads only P + registers).
// ---------------------------------------------------------------------------
__global__ __launch_bounds__(256) void k2_out(
    const short* __restrict__ adjm, const short* __restrict__ xbf,
    const float* __restrict__ Ast,  const float* __restrict__ b_rm,
    const int* __restrict__ alpha_p,
    const float* __restrict__ w_f,  const float* __restrict__ b_f,
    float* __restrict__ out)
{
    __shared__ short adjs[64 * 72];     // [i][j] ready-adj bf16      (9.2 KB)
    __shared__ short xT[64 * 72 + 32];  // [c][j], off c*72+(c>>4)*8  (9.3 KB)
    __shared__ short P[64 * 104];       // [i][c]                    (13.3 KB)

    const int b   = blockIdx.x;         // pairs 2b, 2b+1
    const int tid = threadIdx.x;
    const int l = tid & 63, w = tid >> 6;
    const int lr = l & 15, lg = l >> 4;

    const float alpha = alpha_decode(alpha_p);

    const int row0 = tid >> 3;          // 0..31
    const int row1 = row0 + 32;         // 32..63
    const int c8   = (tid & 7) * 8;
    const int jx   = tid >> 2;
    const int cx0  = (tid & 3) * 16;
    const int gx0  = (cx0 >> 4) * 8;

    const int p0 = 2 * b,      p1 = 2 * b + 1;
    const int t0 = p0 & 63,    t1 = p1 & 63;

    // ---- w_f / b_f / ones fragments: shared across both pairs
    const int o = w * 16 + lr;
    bf16x8 afw[3];
#pragma unroll
    for (int ks = 0; ks < 2; ++ks)
        afw[ks] = cvt8(w_f + o * 64 + ks * 32 + lg * 8);
    {
        bf16x8 ab2 = {0, 0, 0, 0, 0, 0, 0, 0};
        if (lg == 0) ab2[0] = f2bf(b_f[o]);
        afw[2] = ab2;
    }
    bf16x8 ones = {0, 0, 0, 0, 0, 0, 0, 0};
    if (lr == 0) {
#pragma unroll
        for (int d = 0; d < 8; ++d) ones[d] = (short)0x3F80;
    }

    // ---- issue pair0 loads
    {
        const short* Ab = adjm + ((size_t)p0 << 12);
        const float* At = Ast  + ((size_t)t0 << 12);
        const short* Xb = xbf  + ((size_t)p0 << 12);
        bf16x8 sA  = *(const bf16x8*)(Ab + row0 * 64 + c8);
        float4 aA0 = *(const float4*)(At + row0 * 64 + c8);
        float4 aA1 = *(const float4*)(At + row0 * 64 + c8 + 4);
        bf16x8 sB  = *(const bf16x8*)(Ab + row1 * 64 + c8);
        float4 aB0 = *(const float4*)(At + row1 * 64 + c8);
        float4 aB1 = *(const float4*)(At + row1 * 64 + c8 + 4);
        bf16x8 xrA = *(const bf16x8*)(Xb + jx * 64 + cx0);
        bf16x8 xrB = *(const bf16x8*)(Xb + jx * 64 + cx0 + 8);
        const float ab0 = alpha * b_rm[t0];

        *(bf16x8*)(adjs + row0 * 72 + c8) = fuse8(sA, aA0, aA1, ab0);
        *(bf16x8*)(adjs + row1 * 72 + c8) = fuse8(sB, aB0, aB1, ab0);
#pragma unroll
        for (int d = 0; d < 8; ++d) {
            xT[(cx0 + d) * 72 + gx0 + jx]     = xrA[d];
            xT[(cx0 + 8 + d) * 72 + gx0 + jx] = xrB[d];
        }
        if (tid < 128) {
            int row = tid >> 1, cz = 80 + (tid & 1) * 8;
            bf16x8 z = {0, 0, 0, 0, 0, 0, 0, 0};
            *(bf16x8*)(P + row * 104 + cz) = z;      // zero once; never clobbered
        }
    }
    __syncthreads();

    // ---- hoist pair0 fragments
    bf16x8 adjA[4][2], bx[2];
#pragma unroll
    for (int mt = 0; mt < 4; ++mt)
#pragma unroll
        for (int ks = 0; ks < 2; ++ks)
            adjA[mt][ks] = *(const bf16x8*)(adjs + (mt * 16 + lr) * 72
                                            + ks * 32 + lg * 8);
#pragma unroll
    for (int ks = 0; ks < 2; ++ks)
        bx[ks] = *(const bf16x8*)(xT + (w * 16 + lr) * 72 + w * 8
                                  + ks * 32 + lg * 8);

    // ---- T14: issue pair1 global loads NOW (in flight during pair0 MFMAs)
    const short* Ab1 = adjm + ((size_t)p1 << 12);
    const float* At1 = Ast  + ((size_t)t1 << 12);
    const short* Xb1 = xbf  + ((size_t)p1 << 12);
    bf16x8 sA1  = *(const bf16x8*)(Ab1 + row0 * 64 + c8);
    float4 aA01 = *(const float4*)(At1 + row0 * 64 + c8);
    float4 aA11 = *(const float4*)(At1 + row0 * 64 + c8 + 4);
    bf16x8 sB1  = *(const bf16x8*)(Ab1 + row1 * 64 + c8);
    float4 aB01 = *(const float4*)(At1 + row1 * 64 + c8);
    float4 aB11 = *(const float4*)(At1 + row1 * 64 + c8 + 4);
    bf16x8 xrA1 = *(const bf16x8*)(Xb1 + jx * 64 + cx0);
    bf16x8 xrB1 = *(const bf16x8*)(Xb1 + jx * 64 + cx0 + 8);
    const float ab1 = alpha * b_rm[t1];

    // ---- pair0 phase 1: P = adj @ x  (wave w -> c-tile w; wave0 ones-col)
    {
        f32x4 acc[4];
#pragma unroll
        for (int mt = 0; mt < 4; ++mt) acc[mt] = (f32x4){0.f, 0.f, 0.f, 0.f};
#pragma unroll
        for (int ks = 0; ks < 2; ++ks)
#pragma unroll
            for (int mt = 0; mt < 4; ++mt)
                acc[mt] = MFMA16(adjA[mt][ks], bx[ks], acc[mt]);   // D[i][c]
#pragma unroll
        for (int mt = 0; mt < 4; ++mt)
#pragma unroll
            for (int e = 0; e < 4; ++e)
                P[(mt * 16 + lg * 4 + e) * 104 + w * 16 + lr] = f2bf(acc[mt][e]);
        if (w == 0) {
            f32x4 accO[4];
#pragma unroll
            for (int mt = 0; mt < 4; ++mt) accO[mt] = (f32x4){0.f, 0.f, 0.f, 0.f};
#pragma unroll
            for (int ks = 0; ks < 2; ++ks)
#pragma unroll
                for (int mt = 0; mt < 4; ++mt)
                    accO[mt] = MFMA16(adjA[mt][ks], ones, accO[mt]);
#pragma unroll
            for (int mt = 0; mt < 4; ++mt)
#pragma unroll
                for (int e = 0; e < 4; ++e)
                    P[(mt * 16 + lg * 4 + e) * 104 + 64 + lr] = f2bf(accO[mt][e]);
        }
    }
    __syncthreads();

    // ---- pair0 phase 2: out = W_aug @ P
    {
        float* Ob = out + ((size_t)p0 << 12);
#pragma unroll
        for (int nt = 0; nt < 4; ++nt) {
            const int i = nt * 16 + lr;
            bf16x8 bP[3];
#pragma unroll
            for (int ks = 0; ks < 3; ++ks)
                bP[ks] = *(const bf16x8*)(P + i * 104 + ks * 32 + lg * 8);
            f32x4 acc = (f32x4){0.f, 0.f, 0.f, 0.f};
#pragma unroll
            for (int ks = 0; ks < 3; ++ks)
                acc = MFMA16(afw[ks], bP[ks], acc);             // D[o][i]
            *(f32x4*)(Ob + i * 64 + w * 16 + lg * 4) = acc;
        }
    }
    // adjs/xT rewrite is safe: phase2 reads only P + registers.
    *(bf16x8*)(adjs + row0 * 72 + c8) = fuse8(sA1, aA01, aA11, ab1);
    *(bf16x8*)(adjs + row1 * 72 + c8) = fuse8(sB1, aB01, aB11, ab1);
#pragma unroll
    for (int d = 0; d < 8; ++d) {
        xT[(cx0 + d) * 72 + gx0 + jx]     = xrA1[d];
        xT[(cx0 + 8 + d) * 72 + gx0 + jx] = xrB1[d];
    }
    __syncthreads();                    // all phase1(P-write)+phase2 done + LDS ready

    // ---- hoist pair1 fragments
#pragma unroll
    for (int mt = 0; mt < 4; ++mt)
#pragma unroll
        for (int ks = 0; ks < 2; ++ks)
            adjA[mt][ks] = *(const bf16x8*)(adjs + (mt * 16 + lr) * 72
                                            + ks * 32 + lg * 8);
#pragma unroll
    for (int ks = 0; ks < 2; ++ks)
        bx[ks] = *(const bf16x8*)(xT + (w * 16 + lr) * 72 + w * 8
                                  + ks * 32 + lg * 8);

    // ---- pair1 phase 1
    {
        f32x4 acc[4];
#pragma unroll
        for (int mt = 0; mt < 4; ++mt) acc[mt] = (f32x4){0.f, 0.f, 0.f, 0.f};
#pragma unroll
        for (int ks = 0; ks < 2; ++ks)
#pragma unroll
            for (int mt = 0; mt < 4; ++mt)
                acc[mt] = MFMA16(adjA[mt][ks], bx[ks], acc[mt]);
#pragma unroll
        for (int mt = 0; mt < 4; ++mt)
#pragma unroll
            for (int e = 0; e < 4; ++e)
                P[(mt * 16 + lg * 4 + e) * 104 + w * 16 + lr] = f2bf(acc[mt][e]);
        if (w == 0) {
            f32x4 accO[4];
#pragma unroll
            for (int mt = 0; mt < 4; ++mt) accO[mt] = (f32x4){0.f, 0.f, 0.f, 0.f};
#pragma unroll
            for (int ks = 0; ks < 2; ++ks)
#pragma unroll
                for (int mt = 0; mt < 4; ++mt)
                    accO[mt] = MFMA16(adjA[mt][ks], ones, accO[mt]);
#pragma unroll
            for (int mt = 0; mt < 4; ++mt)
#pragma unroll
                for (int e = 0; e < 4; ++e)
                    P[(mt * 16 + lg * 4 + e) * 104 + 64 + lr] = f2bf(accO[mt][e]);
        }
    }
    __syncthreads();

    // ---- pair1 phase 2
    {
        float* Ob = out + ((size_t)p1 << 12);
#pragma unroll
        for (int nt = 0; nt < 4; ++nt) {
            const int i = nt * 16 + lr;
            bf16x8 bP[3];
#pragma unroll
            for (int ks = 0; ks < 3; ++ks)
                bP[ks] = *(const bf16x8*)(P + i * 104 + ks * 32 + lg * 8);
            f32x4 acc = (f32x4){0.f, 0.f, 0.f, 0.f};
#pragma unroll
            for (int ks = 0; ks < 3; ++ks)
                acc = MFMA16(afw[ks], bP[ks], acc);             // D[o][i]
            *(f32x4*)(Ob + i * 64 + w * 16 + lg * 4) = acc;
        }
    }
}

// ---------------------------------------------------------------------------
extern "C" void kernel_launch(void* const* d_in, const int* in_sizes, int n_in,
                              void* d_out, int out_size, void* d_ws, size_t ws_size,
                              hipStream_t stream)
{
    const float* x    = (const float*)d_in[0];
    const float* A    = (const float*)d_in[1];
    const float* w_m1 = (const float*)d_in[2];
    const float* b_m1 = (const float*)d_in[3];
    const float* w_m2 = (const float*)d_in[4];
    const float* b_m2 = (const float*)d_in[5];
    const float* w_rm = (const float*)d_in[6];
    const float* b_rm = (const float*)d_in[7];
    const float* w_f  = (const float*)d_in[8];
    const float* b_f  = (const float*)d_in[9];
    const int*   alpha = (const int*)d_in[10];

    // ws layout: adjm [0,33.5MB), xbf [34,66MB), m1T [66,68), m2T [68,70).
    char* ws = (char*)d_ws;
    short* adjm = (short*)(ws);
    short* xbf = (short*)(ws + (size_t)34 * 1024 * 1024);
    float* m1T = (float*)(ws + (size_t)66 * 1024 * 1024);
    float* m2T = (float*)(ws + (size_t)68 * 1024 * 1024);
    float* out = (float*)d_out;

    k0_stream2<<<dim3(512), dim3(512), 0, stream>>>(x, w_m1, b_m1, w_m2, b_m2,
                                                    xbf, m1T, m2T);
    k1_adj<<<dim3(512), dim3(512), 0, stream>>>(w_rm, m1T, m2T, alpha, adjm);
    k2_out<<<dim3(2048), dim3(256), 0, stream>>>(adjm, xbf, A, b_rm, alpha,
                                                 w_f, b_f, out);
}

// Round 18
// 67.389 us; speedup vs baseline: 1.5615x; 1.0226x over previous
//
#include <hip/hip_runtime.h>
#include <hip/hip_bf16.h>

// ---------------------------------------------------------------------------
// DSTDGC R18.
// k0_stream2: unchanged (R16).
// k1_adj: m1r global loads issued BEFORE staging (latency hides under stage).
// k2: T14 depth-4 — block = 4 consecutive (n,t) pairs, fully unrolled;
//     next pair's global loads issued during current pair's MFMA phases;
//     single LDS buffer, barrier-separated overwrites (R17-proven ordering).
// ---------------------------------------------------------------------------

typedef float  f32x4  __attribute__((ext_vector_type(4)));
typedef short  bf16x8 __attribute__((ext_vector_type(8)));
typedef short  bf16x4 __attribute__((ext_vector_type(4)));

static __device__ __forceinline__ short f2bf(float f) {
    __hip_bfloat16 h = __float2bfloat16(f);     // RNE; compiler packs pairs
    return *reinterpret_cast<short*>(&h);
}

static __device__ __forceinline__ float bf2f(short s) {
    return __uint_as_float(((unsigned)(unsigned short)s) << 16);
}

static __device__ __forceinline__ bf16x8 cvt8f(const float4 a, const float4 b) {
    bf16x8 r;
    r[0] = f2bf(a.x); r[1] = f2bf(a.y); r[2] = f2bf(a.z); r[3] = f2bf(a.w);
    r[4] = f2bf(b.x); r[5] = f2bf(b.y); r[6] = f2bf(b.z); r[7] = f2bf(b.w);
    return r;
}

static __device__ __forceinline__ bf16x8 cvt8(const float* p) {
    return cvt8f(*(const float4*)p, *(const float4*)(p + 4));
}

// tanh(x) = 1 - 2/(exp(2x)+1)
static __device__ __forceinline__ float tanh_fast(float x) {
    float e = __expf(2.0f * x);
    return 1.0f - 2.0f * __builtin_amdgcn_rcpf(e + 1.0f);
}

static __device__ __forceinline__ float dot4(float4 a, float4 b) {
    return a.x * b.x + a.y * b.y + a.z * b.z + a.w * b.w;
}

static __device__ __forceinline__ float alpha_decode(const int* p) {
    int raw = p[0];
    unsigned ur = (unsigned)(raw < 0 ? -raw : raw);
    return (ur < (1u << 23)) ? (float)raw : __int_as_float(raw);
}

static __device__ __forceinline__ bf16x8 fuse8(bf16x8 s, float4 a0, float4 a1,
                                               float ab) {
    bf16x8 r;
    r[0] = f2bf(bf2f(s[0]) + a0.x + ab);
    r[1] = f2bf(bf2f(s[1]) + a0.y + ab);
    r[2] = f2bf(bf2f(s[2]) + a0.z + ab);
    r[3] = f2bf(bf2f(s[3]) + a0.w + ab);
    r[4] = f2bf(bf2f(s[4]) + a1.x + ab);
    r[5] = f2bf(bf2f(s[5]) + a1.y + ab);
    r[6] = f2bf(bf2f(s[6]) + a1.z + ab);
    r[7] = f2bf(bf2f(s[7]) + a1.w + ab);
    return r;
}

#define MFMA16(a, b, c) __builtin_amdgcn_mfma_f32_16x16x32_bf16((a), (b), (c), 0, 0, 0)

// ---------------------------------------------------------------------------
// K0_stream2: block b = n*8 + vc (v0 = vc*8), 512 threads.  (R16, unchanged)
// ---------------------------------------------------------------------------
__global__ __launch_bounds__(512) void k0_stream2(
    const float* __restrict__ x,
    const float* __restrict__ w_m1, const float* __restrict__ b_m1,
    const float* __restrict__ w_m2, const float* __restrict__ b_m2,
    short* __restrict__ xbf, float* __restrict__ m1T, float* __restrict__ m2T)
{
    __shared__ float msT[4][8][68];     // [sel][vv][t], stride 68 (f4-aligned)

    const int b   = blockIdx.x;         // n*8 + vc
    const int n   = b >> 3;
    const int v0  = (b & 7) * 8;
    const int tid = threadIdx.x;
    const int tl  = tid >> 6;           // 0..7
    const int vv  = (tid >> 3) & 7;     // 0..7
    const int cg  = tid & 7;            // 0..7
    const int c0  = cg * 8;

    const float4 w10 = *(const float4*)(w_m1 + c0);
    const float4 w11 = *(const float4*)(w_m1 + c0 + 4);
    const float4 w20 = *(const float4*)(w_m1 + 64 + c0);
    const float4 w21 = *(const float4*)(w_m1 + 64 + c0 + 4);
    const float4 w30 = *(const float4*)(w_m2 + c0);
    const float4 w31 = *(const float4*)(w_m2 + c0 + 4);
    const float4 w40 = *(const float4*)(w_m2 + 64 + c0);
    const float4 w41 = *(const float4*)(w_m2 + 64 + c0 + 4);

#pragma unroll 2
    for (int it = 0; it < 8; ++it) {
        const int t = it * 8 + tl;
        const size_t R = ((size_t)(n * 64 + t)) * 64 + (v0 + vv);
        const float* xp = x + (R << 6) + c0;
        const float4 a0 = *(const float4*)xp;
        const float4 a1 = *(const float4*)(xp + 4);

        float s0 = dot4(a0, w10) + dot4(a1, w11);
        float s1 = dot4(a0, w20) + dot4(a1, w21);
        float s2 = dot4(a0, w30) + dot4(a1, w31);
        float s3 = dot4(a0, w40) + dot4(a1, w41);

        *(bf16x8*)(xbf + (R << 6) + c0) = cvt8f(a0, a1);

#pragma unroll
        for (int m = 1; m < 8; m <<= 1) {
            s0 += __shfl_xor(s0, m);
            s1 += __shfl_xor(s1, m);
            s2 += __shfl_xor(s2, m);
            s3 += __shfl_xor(s3, m);
        }
        if (cg < 4) {                   // per-t regions disjoint -> no barrier
            float s = (cg == 0) ? s0 : (cg == 1) ? s1 : (cg == 2) ? s2 : s3;
            msT[cg][vv][t] = s;
        }
    }
    __syncthreads();

    {
        const int m   = tid >> 8;        // 0: m1, 1: m2
        const int rem = tid & 255;
        const int vv2 = rem >> 5;        // 0..7
        const int k0  = (rem & 31) * 4;  // 0..124
        const int r   = k0 >> 6;
        const int sel = m * 2 + r;
        const int t0  = k0 & 63;
        float4 val = *(const float4*)&msT[sel][vv2][t0];
        const float bias = (m == 0) ? b_m1[r] : b_m2[r];
        val.x += bias; val.y += bias; val.z += bias; val.w += bias;
        float* dst = ((m == 0) ? m1T : m2T) + n * 8192 + (v0 + vv2) * 128 + k0;
        *(float4*)dst = val;
    }
}

// ---------------------------------------------------------------------------
// K1: block (n, i-chunk of 8), 512 thr, grid 512.  m1r loads issued early.
// ---------------------------------------------------------------------------
__global__ __launch_bounds__(512) void k1_adj(
    const float* __restrict__ w_rm,
    const float* __restrict__ m1T,  const float* __restrict__ m2T,
    const int* __restrict__ alpha_p,
    short* __restrict__ adjm)
{
    __shared__ float m2s[64 * 132];     // [j][k] f32 stride 132     (33.8 KB)
    __shared__ short wrs[64 * 132];     // [t][k] bf16*alpha, s=132  (16.9 KB)

    const int b   = blockIdx.x;
    const int n   = b >> 3;
    const int i0  = (b & 7) * 8;
    const int tid = threadIdx.x;
    const int l = tid & 63, w = tid >> 6;
    const int lr = l & 15, lg = l >> 4;
    const int ig = i0 + w;

    const float alpha = alpha_decode(alpha_p);

    // ---- issue m1 row loads FIRST (independent; latency hides under staging)
    float4 m1r[8];
#pragma unroll
    for (int kt = 0; kt < 4; ++kt) {
        const float* p = m1T + n * 8192 + ig * 128 + kt * 32 + lg * 8;
        m1r[kt * 2 + 0] = *(const float4*)p;
        m1r[kt * 2 + 1] = *(const float4*)(p + 4);
    }

    {
        const float4* src = (const float4*)(m2T + n * 8192);
        for (int it = tid; it < 2048; it += 512) {
            int j = it >> 5, q = it & 31;
            *(float4*)(m2s + j * 132 + q * 4) = src[it];
        }
    }
    {
        const float4* src = (const float4*)w_rm;
        for (int it = tid; it < 2048; it += 512) {
            int t = it >> 5, q = it & 31;
            float4 v = src[it];
            bf16x4 pv;
            pv[0] = f2bf(alpha * v.x);
            pv[1] = f2bf(alpha * v.y);
            pv[2] = f2bf(alpha * v.z);
            pv[3] = f2bf(alpha * v.w);
            *(bf16x4*)(wrs + t * 132 + q * 4) = pv;
        }
    }
    __syncthreads();

    short* adjb = adjm + ((size_t)n << 18) + (ig << 6);

#pragma unroll 1
    for (int jt = 0; jt < 4; ++jt) {
        const float* m2row = m2s + (jt * 16 + lr) * 132;
        bf16x8 bfr[4];
#pragma unroll
        for (int kt = 0; kt < 4; ++kt) {
            const int k0 = kt * 32 + lg * 8;
            float4 b0 = *(const float4*)(m2row + k0);
            float4 b1 = *(const float4*)(m2row + k0 + 4);
            float4 a0 = m1r[kt * 2], a1 = m1r[kt * 2 + 1];
            bfr[kt][0] = f2bf(tanh_fast(a0.x - b0.x));
            bfr[kt][1] = f2bf(tanh_fast(a0.y - b0.y));
            bfr[kt][2] = f2bf(tanh_fast(a0.z - b0.z));
            bfr[kt][3] = f2bf(tanh_fast(a0.w - b0.w));
            bfr[kt][4] = f2bf(tanh_fast(a1.x - b1.x));
            bfr[kt][5] = f2bf(tanh_fast(a1.y - b1.y));
            bfr[kt][6] = f2bf(tanh_fast(a1.z - b1.z));
            bfr[kt][7] = f2bf(tanh_fast(a1.w - b1.w));
        }

        const int j0 = jt * 16 + lg * 4;
#pragma unroll
        for (int q = 0; q < 4; ++q) {
            const int tq = q * 16 + lr;
            bf16x8 af[4];
#pragma unroll
            for (int kt = 0; kt < 4; ++kt)
                af[kt] = *(const bf16x8*)(wrs + tq * 132 + kt * 32 + lg * 8);
            f32x4 acc = (f32x4){0.f, 0.f, 0.f, 0.f};
#pragma unroll
            for (int kt = 0; kt < 4; ++kt)
                acc = MFMA16(bfr[kt], af[kt], acc);             // D[j][t]
            bf16x4 pv;
            pv[0] = f2bf(acc[0]);
            pv[1] = f2bf(acc[1]);
            pv[2] = f2bf(acc[2]);
            pv[3] = f2bf(acc[3]);
            *(bf16x4*)(adjb + ((size_t)tq << 12) + j0) = pv;    // 8B store
        }
    }
}

// ---------------------------------------------------------------------------
// K2: block = FOUR consecutive (n,t) pairs, 256 thr, grid 1024.  T14 depth-4:
//   next pair's loads issued during current pair's MFMAs; single LDS buffer,
//   2 barriers/pair, phase2 reads only P (adjs/xT rewrite race-free).
// ---------------------------------------------------------------------------
__global__ __launch_bounds__(256) void k2_out(
    const short* __restrict__ adjm, const short* __restrict__ xbf,
    const float* __restrict__ Ast,  const float* __restrict__ b_rm,
    const int* __restrict__ alpha_p,
    const float* __restrict__ w_f,  const float* __restrict__ b_f,
    float* __restrict__ out)
{
    __shared__ short adjs[64 * 72];     // [i][j] ready-adj bf16      (9.2 KB)
    __shared__ short xT[64 * 72 + 32];  // [c][j], off c*72+(c>>4)*8  (9.3 KB)
    __shared__ short P[64 * 104];       // [i][c]                    (13.3 KB)

    const int b   = blockIdx.x;         // pairs 4b .. 4b+3
    const int tid = threadIdx.x;
    const int l = tid & 63, w = tid >> 6;
    const int lr = l & 15, lg = l >> 4;

    const float alpha = alpha_decode(alpha_p);

    const int row0 = tid >> 3;          // 0..31
    const int row1 = row0 + 32;         // 32..63
    const int c8   = (tid & 7) * 8;
    const int jx   = tid >> 2;
    const int cx0  = (tid & 3) * 16;
    const int gx0  = (cx0 >> 4) * 8;

    // ---- w_f / b_f / ones fragments: shared across all 4 pairs
    const int o = w * 16 + lr;
    bf16x8 afw[3];
#pragma unroll
    for (int ks = 0; ks < 2; ++ks)
        afw[ks] = cvt8(w_f + o * 64 + ks * 32 + lg * 8);
    {
        bf16x8 ab2 = {0, 0, 0, 0, 0, 0, 0, 0};
        if (lg == 0) ab2[0] = f2bf(b_f[o]);
        afw[2] = ab2;
    }
    bf16x8 ones = {0, 0, 0, 0, 0, 0, 0, 0};
    if (lr == 0) {
#pragma unroll
        for (int d = 0; d < 8; ++d) ones[d] = (short)0x3F80;
    }

    // ---- pair-prefetch registers (live within one loop body only)
    bf16x8 sA, sB, xrA, xrB;
    float4 aA0, aA1, aB0, aB1;
    float  ab;

    // ---- load + stage pair 4b+0
    {
        const int p = 4 * b, t = p & 63;
        const short* Ab = adjm + ((size_t)p << 12);
        const float* At = Ast  + ((size_t)t << 12);
        const short* Xb = xbf  + ((size_t)p << 12);
        sA  = *(const bf16x8*)(Ab + row0 * 64 + c8);
        aA0 = *(const float4*)(At + row0 * 64 + c8);
        aA1 = *(const float4*)(At + row0 * 64 + c8 + 4);
        sB  = *(const bf16x8*)(Ab + row1 * 64 + c8);
        aB0 = *(const float4*)(At + row1 * 64 + c8);
        aB1 = *(const float4*)(At + row1 * 64 + c8 + 4);
        xrA = *(const bf16x8*)(Xb + jx * 64 + cx0);
        xrB = *(const bf16x8*)(Xb + jx * 64 + cx0 + 8);
        ab  = alpha * b_rm[t];
    }
    *(bf16x8*)(adjs + row0 * 72 + c8) = fuse8(sA, aA0, aA1, ab);
    *(bf16x8*)(adjs + row1 * 72 + c8) = fuse8(sB, aB0, aB1, ab);
#pragma unroll
    for (int d = 0; d < 8; ++d) {
        xT[(cx0 + d) * 72 + gx0 + jx]     = xrA[d];
        xT[(cx0 + 8 + d) * 72 + gx0 + jx] = xrB[d];
    }
    if (tid < 128) {
        int row = tid >> 1, cz = 80 + (tid & 1) * 8;
        bf16x8 z = {0, 0, 0, 0, 0, 0, 0, 0};
        *(bf16x8*)(P + row * 104 + cz) = z;          // zero once
    }
    __syncthreads();

#pragma unroll
    for (int pp = 0; pp < 4; ++pp) {
        const int pair = 4 * b + pp;

        // ---- hoist current fragments from LDS
        bf16x8 adjA[4][2], bx[2];
#pragma unroll
        for (int mt = 0; mt < 4; ++mt)
#pragma unroll
            for (int ks = 0; ks < 2; ++ks)
                adjA[mt][ks] = *(const bf16x8*)(adjs + (mt * 16 + lr) * 72
                                                + ks * 32 + lg * 8);
#pragma unroll
        for (int ks = 0; ks < 2; ++ks)
            bx[ks] = *(const bf16x8*)(xT + (w * 16 + lr) * 72 + w * 8
                                      + ks * 32 + lg * 8);

        // ---- T14: issue next pair's global loads (in flight during MFMAs)
        if (pp < 3) {
            const int pn = pair + 1, tn = pn & 63;
            const short* Ab = adjm + ((size_t)pn << 12);
            const float* At = Ast  + ((size_t)tn << 12);
            const short* Xb = xbf  + ((size_t)pn << 12);
            sA  = *(const bf16x8*)(Ab + row0 * 64 + c8);
            aA0 = *(const float4*)(At + row0 * 64 + c8);
            aA1 = *(const float4*)(At + row0 * 64 + c8 + 4);
            sB  = *(const bf16x8*)(Ab + row1 * 64 + c8);
            aB0 = *(const float4*)(At + row1 * 64 + c8);
            aB1 = *(const float4*)(At + row1 * 64 + c8 + 4);
            xrA = *(const bf16x8*)(Xb + jx * 64 + cx0);
            xrB = *(const bf16x8*)(Xb + jx * 64 + cx0 + 8);
            ab  = alpha * b_rm[tn];
        }

        // ---- phase 1: P = adj @ x  (wave w -> c-tile w; wave0 ones-col)
        {
            f32x4 acc[4];
#pragma unroll
            for (int mt = 0; mt < 4; ++mt) acc[mt] = (f32x4){0.f, 0.f, 0.f, 0.f};
#pragma unroll
            for (int ks = 0; ks < 2; ++ks)
#pragma unroll
                for (int mt = 0; mt < 4; ++mt)
                    acc[mt] = MFMA16(adjA[mt][ks], bx[ks], acc[mt]);   // D[i][c]
#pragma unroll
            for (int mt = 0; mt < 4; ++mt)
#pragma unroll
                for (int e = 0; e < 4; ++e)
                    P[(mt * 16 + lg * 4 + e) * 104 + w * 16 + lr] =
                        f2bf(acc[mt][e]);
            if (w == 0) {
                f32x4 accO[4];
#pragma unroll
                for (int mt = 0; mt < 4; ++mt)
                    accO[mt] = (f32x4){0.f, 0.f, 0.f, 0.f};
#pragma unroll
                for (int ks = 0; ks < 2; ++ks)
#pragma unroll
                    for (int mt = 0; mt < 4; ++mt)
                        accO[mt] = MFMA16(adjA[mt][ks], ones, accO[mt]);
#pragma unroll
                for (int mt = 0; mt < 4; ++mt)
#pragma unroll
                    for (int e = 0; e < 4; ++e)
                        P[(mt * 16 + lg * 4 + e) * 104 + 64 + lr] =
                            f2bf(accO[mt][e]);
            }
        }
        __syncthreads();

        // ---- phase 2: out = W_aug @ P  (reads only P + registers)
        {
            float* Ob = out + ((size_t)pair << 12);
#pragma unroll
            for (int nt = 0; nt < 4; ++nt) {
                const int i = nt * 16 + lr;
                bf16x8 bP[3];
#pragma unroll
                for (int ks = 0; ks < 3; ++ks)
                    bP[ks] = *(const bf16x8*)(P + i * 104 + ks * 32 + lg * 8);
                f32x4 acc = (f32x4){0.f, 0.f, 0.f, 0.f};
#pragma unroll
                for (int ks = 0; ks < 3; ++ks)
                    acc = MFMA16(afw[ks], bP[ks], acc);         // D[o][i]
                *(f32x4*)(Ob + i * 64 + w * 16 + lg * 4) = acc;
            }
        }
        // ---- stage next pair (safe: phase2 reads only P)
        if (pp < 3) {
            *(bf16x8*)(adjs + row0 * 72 + c8) = fuse8(sA, aA0, aA1, ab);
            *(bf16x8*)(adjs + row1 * 72 + c8) = fuse8(sB, aB0, aB1, ab);
#pragma unroll
            for (int d = 0; d < 8; ++d) {
                xT[(cx0 + d) * 72 + gx0 + jx]     = xrA[d];
                xT[(cx0 + 8 + d) * 72 + gx0 + jx] = xrB[d];
            }
        }
        __syncthreads();    // P-reads done before next phase1; LDS staged
    }
}

// ---------------------------------------------------------------------------
extern "C" void kernel_launch(void* const* d_in, const int* in_sizes, int n_in,
                              void* d_out, int out_size, void* d_ws, size_t ws_size,
                              hipStream_t stream)
{
    const float* x    = (const float*)d_in[0];
    const float* A    = (const float*)d_in[1];
    const float* w_m1 = (const float*)d_in[2];
    const float* b_m1 = (const float*)d_in[3];
    const float* w_m2 = (const float*)d_in[4];
    const float* b_m2 = (const float*)d_in[5];
    const float* w_rm = (const float*)d_in[6];
    const float* b_rm = (const float*)d_in[7];
    const float* w_f  = (const float*)d_in[8];
    const float* b_f  = (const float*)d_in[9];
    const int*   alpha = (const int*)d_in[10];

    // ws layout: adjm [0,33.5MB), xbf [34,66MB), m1T [66,68), m2T [68,70).
    char* ws = (char*)d_ws;
    short* adjm = (short*)(ws);
    short* xbf = (short*)(ws + (size_t)34 * 1024 * 1024);
    float* m1T = (float*)(ws + (size_t)66 * 1024 * 1024);
    float* m2T = (float*)(ws + (size_t)68 * 1024 * 1024);
    float* out = (float*)d_out;

    k0_stream2<<<dim3(512), dim3(512), 0, stream>>>(x, w_m1, b_m1, w_m2, b_m2,
                                                    xbf, m1T, m2T);
    k1_adj<<<dim3(512), dim3(512), 0, stream>>>(w_rm, m1T, m2T, alpha, adjm);
    k2_out<<<dim3(1024), dim3(256), 0, stream>>>(adjm, xbf, A, b_rm, alpha,
                                                 w_f, b_f, out);
}

// Round 19
// 63.996 us; speedup vs baseline: 1.6443x; 1.0530x over previous
//
#include <hip/hip_runtime.h>
#include <hip/hip_bf16.h>

// ---------------------------------------------------------------------------
// DSTDGC R19.
// xbf intermediate ELIMINATED: x (67MB) is L3-resident after k0's read, so
// k2 reads x f32 directly and converts during its xT staging pass.
// k0_proj: m-projections only (67MB in, 4MB out).
// k1_adj: unchanged (R18).
// k2: x f32 source for xT staging + T14 depth-4 (R18 structure).
// ---------------------------------------------------------------------------

typedef float  f32x4  __attribute__((ext_vector_type(4)));
typedef short  bf16x8 __attribute__((ext_vector_type(8)));
typedef short  bf16x4 __attribute__((ext_vector_type(4)));

static __device__ __forceinline__ short f2bf(float f) {
    __hip_bfloat16 h = __float2bfloat16(f);     // RNE; compiler packs pairs
    return *reinterpret_cast<short*>(&h);
}

static __device__ __forceinline__ float bf2f(short s) {
    return __uint_as_float(((unsigned)(unsigned short)s) << 16);
}

static __device__ __forceinline__ bf16x8 cvt8f(const float4 a, const float4 b) {
    bf16x8 r;
    r[0] = f2bf(a.x); r[1] = f2bf(a.y); r[2] = f2bf(a.z); r[3] = f2bf(a.w);
    r[4] = f2bf(b.x); r[5] = f2bf(b.y); r[6] = f2bf(b.z); r[7] = f2bf(b.w);
    return r;
}

static __device__ __forceinline__ bf16x8 cvt8(const float* p) {
    return cvt8f(*(const float4*)p, *(const float4*)(p + 4));
}

// tanh(x) = 1 - 2/(exp(2x)+1)
static __device__ __forceinline__ float tanh_fast(float x) {
    float e = __expf(2.0f * x);
    return 1.0f - 2.0f * __builtin_amdgcn_rcpf(e + 1.0f);
}

static __device__ __forceinline__ float dot4(float4 a, float4 b) {
    return a.x * b.x + a.y * b.y + a.z * b.z + a.w * b.w;
}

static __device__ __forceinline__ float alpha_decode(const int* p) {
    int raw = p[0];
    unsigned ur = (unsigned)(raw < 0 ? -raw : raw);
    return (ur < (1u << 23)) ? (float)raw : __int_as_float(raw);
}

static __device__ __forceinline__ bf16x8 fuse8(bf16x8 s, float4 a0, float4 a1,
                                               float ab) {
    bf16x8 r;
    r[0] = f2bf(bf2f(s[0]) + a0.x + ab);
    r[1] = f2bf(bf2f(s[1]) + a0.y + ab);
    r[2] = f2bf(bf2f(s[2]) + a0.z + ab);
    r[3] = f2bf(bf2f(s[3]) + a0.w + ab);
    r[4] = f2bf(bf2f(s[4]) + a1.x + ab);
    r[5] = f2bf(bf2f(s[5]) + a1.y + ab);
    r[6] = f2bf(bf2f(s[6]) + a1.z + ab);
    r[7] = f2bf(bf2f(s[7]) + a1.w + ab);
    return r;
}

#define MFMA16(a, b, c) __builtin_amdgcn_mfma_f32_16x16x32_bf16((a), (b), (c), 0, 0, 0)

// ---------------------------------------------------------------------------
// K0_proj: m-projections only.  Block b = n*8 + vc (v0 = vc*8), 512 thr.
// ---------------------------------------------------------------------------
__global__ __launch_bounds__(512) void k0_proj(
    const float* __restrict__ x,
    const float* __restrict__ w_m1, const float* __restrict__ b_m1,
    const float* __restrict__ w_m2, const float* __restrict__ b_m2,
    float* __restrict__ m1T, float* __restrict__ m2T)
{
    __shared__ float msT[4][8][68];     // [sel][vv][t], stride 68 (f4-aligned)

    const int b   = blockIdx.x;         // n*8 + vc
    const int n   = b >> 3;
    const int v0  = (b & 7) * 8;
    const int tid = threadIdx.x;
    const int tl  = tid >> 6;           // 0..7
    const int vv  = (tid >> 3) & 7;     // 0..7
    const int cg  = tid & 7;            // 0..7
    const int c0  = cg * 8;

    const float4 w10 = *(const float4*)(w_m1 + c0);
    const float4 w11 = *(const float4*)(w_m1 + c0 + 4);
    const float4 w20 = *(const float4*)(w_m1 + 64 + c0);
    const float4 w21 = *(const float4*)(w_m1 + 64 + c0 + 4);
    const float4 w30 = *(const float4*)(w_m2 + c0);
    const float4 w31 = *(const float4*)(w_m2 + c0 + 4);
    const float4 w40 = *(const float4*)(w_m2 + 64 + c0);
    const float4 w41 = *(const float4*)(w_m2 + 64 + c0 + 4);

#pragma unroll 2
    for (int it = 0; it < 8; ++it) {
        const int t = it * 8 + tl;
        const size_t R = ((size_t)(n * 64 + t)) * 64 + (v0 + vv);
        const float* xp = x + (R << 6) + c0;
        const float4 a0 = *(const float4*)xp;
        const float4 a1 = *(const float4*)(xp + 4);

        float s0 = dot4(a0, w10) + dot4(a1, w11);
        float s1 = dot4(a0, w20) + dot4(a1, w21);
        float s2 = dot4(a0, w30) + dot4(a1, w31);
        float s3 = dot4(a0, w40) + dot4(a1, w41);

#pragma unroll
        for (int m = 1; m < 8; m <<= 1) {
            s0 += __shfl_xor(s0, m);
            s1 += __shfl_xor(s1, m);
            s2 += __shfl_xor(s2, m);
            s3 += __shfl_xor(s3, m);
        }
        if (cg < 4) {                   // per-t regions disjoint -> no barrier
            float s = (cg == 0) ? s0 : (cg == 1) ? s1 : (cg == 2) ? s2 : s3;
            msT[cg][vv][t] = s;
        }
    }
    __syncthreads();

    {
        const int m   = tid >> 8;        // 0: m1, 1: m2
        const int rem = tid & 255;
        const int vv2 = rem >> 5;        // 0..7
        const int k0  = (rem & 31) * 4;  // 0..124
        const int r   = k0 >> 6;
        const int sel = m * 2 + r;
        const int t0  = k0 & 63;
        float4 val = *(const float4*)&msT[sel][vv2][t0];
        const float bias = (m == 0) ? b_m1[r] : b_m2[r];
        val.x += bias; val.y += bias; val.z += bias; val.w += bias;
        float* dst = ((m == 0) ? m1T : m2T) + n * 8192 + (v0 + vv2) * 128 + k0;
        *(float4*)dst = val;
    }
}

// ---------------------------------------------------------------------------
// K1: block (n, i-chunk of 8), 512 thr, grid 512.  (R18, unchanged)
// ---------------------------------------------------------------------------
__global__ __launch_bounds__(512) void k1_adj(
    const float* __restrict__ w_rm,
    const float* __restrict__ m1T,  const float* __restrict__ m2T,
    const int* __restrict__ alpha_p,
    short* __restrict__ adjm)
{
    __shared__ float m2s[64 * 132];     // [j][k] f32 stride 132     (33.8 KB)
    __shared__ short wrs[64 * 132];     // [t][k] bf16*alpha, s=132  (16.9 KB)

    const int b   = blockIdx.x;
    const int n   = b >> 3;
    const int i0  = (b & 7) * 8;
    const int tid = threadIdx.x;
    const int l = tid & 63, w = tid >> 6;
    const int lr = l & 15, lg = l >> 4;
    const int ig = i0 + w;

    const float alpha = alpha_decode(alpha_p);

    // ---- issue m1 row loads FIRST (latency hides under staging)
    float4 m1r[8];
#pragma unroll
    for (int kt = 0; kt < 4; ++kt) {
        const float* p = m1T + n * 8192 + ig * 128 + kt * 32 + lg * 8;
        m1r[kt * 2 + 0] = *(const float4*)p;
        m1r[kt * 2 + 1] = *(const float4*)(p + 4);
    }

    {
        const float4* src = (const float4*)(m2T + n * 8192);
        for (int it = tid; it < 2048; it += 512) {
            int j = it >> 5, q = it & 31;
            *(float4*)(m2s + j * 132 + q * 4) = src[it];
        }
    }
    {
        const float4* src = (const float4*)w_rm;
        for (int it = tid; it < 2048; it += 512) {
            int t = it >> 5, q = it & 31;
            float4 v = src[it];
            bf16x4 pv;
            pv[0] = f2bf(alpha * v.x);
            pv[1] = f2bf(alpha * v.y);
            pv[2] = f2bf(alpha * v.z);
            pv[3] = f2bf(alpha * v.w);
            *(bf16x4*)(wrs + t * 132 + q * 4) = pv;
        }
    }
    __syncthreads();

    short* adjb = adjm + ((size_t)n << 18) + (ig << 6);

#pragma unroll 1
    for (int jt = 0; jt < 4; ++jt) {
        const float* m2row = m2s + (jt * 16 + lr) * 132;
        bf16x8 bfr[4];
#pragma unroll
        for (int kt = 0; kt < 4; ++kt) {
            const int k0 = kt * 32 + lg * 8;
            float4 b0 = *(const float4*)(m2row + k0);
            float4 b1 = *(const float4*)(m2row + k0 + 4);
            float4 a0 = m1r[kt * 2], a1 = m1r[kt * 2 + 1];
            bfr[kt][0] = f2bf(tanh_fast(a0.x - b0.x));
            bfr[kt][1] = f2bf(tanh_fast(a0.y - b0.y));
            bfr[kt][2] = f2bf(tanh_fast(a0.z - b0.z));
            bfr[kt][3] = f2bf(tanh_fast(a0.w - b0.w));
            bfr[kt][4] = f2bf(tanh_fast(a1.x - b1.x));
            bfr[kt][5] = f2bf(tanh_fast(a1.y - b1.y));
            bfr[kt][6] = f2bf(tanh_fast(a1.z - b1.z));
            bfr[kt][7] = f2bf(tanh_fast(a1.w - b1.w));
        }

        const int j0 = jt * 16 + lg * 4;
#pragma unroll
        for (int q = 0; q < 4; ++q) {
            const int tq = q * 16 + lr;
            bf16x8 af[4];
#pragma unroll
            for (int kt = 0; kt < 4; ++kt)
                af[kt] = *(const bf16x8*)(wrs + tq * 132 + kt * 32 + lg * 8);
            f32x4 acc = (f32x4){0.f, 0.f, 0.f, 0.f};
#pragma unroll
            for (int kt = 0; kt < 4; ++kt)
                acc = MFMA16(bfr[kt], af[kt], acc);             // D[j][t]
            bf16x4 pv;
            pv[0] = f2bf(acc[0]);
            pv[1] = f2bf(acc[1]);
            pv[2] = f2bf(acc[2]);
            pv[3] = f2bf(acc[3]);
            *(bf16x4*)(adjb + ((size_t)tq << 12) + j0) = pv;    // 8B store
        }
    }
}

// ---------------------------------------------------------------------------
// K2: block = FOUR consecutive (n,t) pairs, 256 thr, grid 1024.  T14 depth-4.
//   x read DIRECTLY as f32 (L3-resident after k0); cvt fused into staging.
// ---------------------------------------------------------------------------
__global__ __launch_bounds__(256) void k2_out(
    const short* __restrict__ adjm, const float* __restrict__ x,
    const float* __restrict__ Ast,  const float* __restrict__ b_rm,
    const int* __restrict__ alpha_p,
    const float* __restrict__ w_f,  const float* __restrict__ b_f,
    float* __restrict__ out)
{
    __shared__ short adjs[64 * 72];     // [i][j] ready-adj bf16      (9.2 KB)
    __shared__ short xT[64 * 72 + 32];  // [c][j], off c*72+(c>>4)*8  (9.3 KB)
    __shared__ short P[64 * 104];       // [i][c]                    (13.3 KB)

    const int b   = blockIdx.x;         // pairs 4b .. 4b+3
    const int tid = threadIdx.x;
    const int l = tid & 63, w = tid >> 6;
    const int lr = l & 15, lg = l >> 4;

    const float alpha = alpha_decode(alpha_p);

    const int row0 = tid >> 3;          // 0..31
    const int row1 = row0 + 32;         // 32..63
    const int c8   = (tid & 7) * 8;
    const int jx   = tid >> 2;
    const int cx0  = (tid & 3) * 16;
    const int gx0  = (cx0 >> 4) * 8;

    // ---- w_f / b_f / ones fragments: shared across all 4 pairs
    const int o = w * 16 + lr;
    bf16x8 afw[3];
#pragma unroll
    for (int ks = 0; ks < 2; ++ks)
        afw[ks] = cvt8(w_f + o * 64 + ks * 32 + lg * 8);
    {
        bf16x8 ab2 = {0, 0, 0, 0, 0, 0, 0, 0};
        if (lg == 0) ab2[0] = f2bf(b_f[o]);
        afw[2] = ab2;
    }
    bf16x8 ones = {0, 0, 0, 0, 0, 0, 0, 0};
    if (lr == 0) {
#pragma unroll
        for (int d = 0; d < 8; ++d) ones[d] = (short)0x3F80;
    }

    // ---- pair-prefetch registers (live within one loop body only)
    bf16x8 sA, sB;
    float4 aA0, aA1, aB0, aB1;
    float4 px0, px1, px2, px3;          // x f32 prefetch (16 f32 = this
    float  ab;                          //   thread's 16 c at row jx)

    // ---- load + stage pair 4b+0
    {
        const int p = 4 * b, t = p & 63;
        const short* Ab = adjm + ((size_t)p << 12);
        const float* At = Ast  + ((size_t)t << 12);
        const float* Xb = x    + ((size_t)p << 12);
        sA  = *(const bf16x8*)(Ab + row0 * 64 + c8);
        aA0 = *(const float4*)(At + row0 * 64 + c8);
        aA1 = *(const float4*)(At + row0 * 64 + c8 + 4);
        sB  = *(const bf16x8*)(Ab + row1 * 64 + c8);
        aB0 = *(const float4*)(At + row1 * 64 + c8);
        aB1 = *(const float4*)(At + row1 * 64 + c8 + 4);
        px0 = *(const float4*)(Xb + jx * 64 + cx0);
        px1 = *(const float4*)(Xb + jx * 64 + cx0 + 4);
        px2 = *(const float4*)(Xb + jx * 64 + cx0 + 8);
        px3 = *(const float4*)(Xb + jx * 64 + cx0 + 12);
        ab  = alpha * b_rm[t];
    }
    {
        bf16x8 xrA = cvt8f(px0, px1);
        bf16x8 xrB = cvt8f(px2, px3);
        *(bf16x8*)(adjs + row0 * 72 + c8) = fuse8(sA, aA0, aA1, ab);
        *(bf16x8*)(adjs + row1 * 72 + c8) = fuse8(sB, aB0, aB1, ab);
#pragma unroll
        for (int d = 0; d < 8; ++d) {
            xT[(cx0 + d) * 72 + gx0 + jx]     = xrA[d];
            xT[(cx0 + 8 + d) * 72 + gx0 + jx] = xrB[d];
        }
    }
    if (tid < 128) {
        int row = tid >> 1, cz = 80 + (tid & 1) * 8;
        bf16x8 z = {0, 0, 0, 0, 0, 0, 0, 0};
        *(bf16x8*)(P + row * 104 + cz) = z;          // zero once
    }
    __syncthreads();

#pragma unroll
    for (int pp = 0; pp < 4; ++pp) {
        const int pair = 4 * b + pp;

        // ---- hoist current fragments from LDS
        bf16x8 adjA[4][2], bx[2];
#pragma unroll
        for (int mt = 0; mt < 4; ++mt)
#pragma unroll
            for (int ks = 0; ks < 2; ++ks)
                adjA[mt][ks] = *(const bf16x8*)(adjs + (mt * 16 + lr) * 72
                                                + ks * 32 + lg * 8);
#pragma unroll
        for (int ks = 0; ks < 2; ++ks)
            bx[ks] = *(const bf16x8*)(xT + (w * 16 + lr) * 72 + w * 8
                                      + ks * 32 + lg * 8);

        // ---- T14: issue next pair's global loads (in flight during MFMAs)
        if (pp < 3) {
            const int pn = pair + 1, tn = pn & 63;
            const short* Ab = adjm + ((size_t)pn << 12);
            const float* At = Ast  + ((size_t)tn << 12);
            const float* Xb = x    + ((size_t)pn << 12);
            sA  = *(const bf16x8*)(Ab + row0 * 64 + c8);
            aA0 = *(const float4*)(At + row0 * 64 + c8);
            aA1 = *(const float4*)(At + row0 * 64 + c8 + 4);
            sB  = *(const bf16x8*)(Ab + row1 * 64 + c8);
            aB0 = *(const float4*)(At + row1 * 64 + c8);
            aB1 = *(const float4*)(At + row1 * 64 + c8 + 4);
            px0 = *(const float4*)(Xb + jx * 64 + cx0);
            px1 = *(const float4*)(Xb + jx * 64 + cx0 + 4);
            px2 = *(const float4*)(Xb + jx * 64 + cx0 + 8);
            px3 = *(const float4*)(Xb + jx * 64 + cx0 + 12);
            ab  = alpha * b_rm[tn];
        }

        // ---- phase 1: P = adj @ x  (wave w -> c-tile w; wave0 ones-col)
        {
            f32x4 acc[4];
#pragma unroll
            for (int mt = 0; mt < 4; ++mt) acc[mt] = (f32x4){0.f, 0.f, 0.f, 0.f};
#pragma unroll
            for (int ks = 0; ks < 2; ++ks)
#pragma unroll
                for (int mt = 0; mt < 4; ++mt)
                    acc[mt] = MFMA16(adjA[mt][ks], bx[ks], acc[mt]);   // D[i][c]
#pragma unroll
            for (int mt = 0; mt < 4; ++mt)
#pragma unroll
                for (int e = 0; e < 4; ++e)
                    P[(mt * 16 + lg * 4 + e) * 104 + w * 16 + lr] =
                        f2bf(acc[mt][e]);
            if (w == 0) {
                f32x4 accO[4];
#pragma unroll
                for (int mt = 0; mt < 4; ++mt)
                    accO[mt] = (f32x4){0.f, 0.f, 0.f, 0.f};
#pragma unroll
                for (int ks = 0; ks < 2; ++ks)
#pragma unroll
                    for (int mt = 0; mt < 4; ++mt)
                        accO[mt] = MFMA16(adjA[mt][ks], ones, accO[mt]);
#pragma unroll
                for (int mt = 0; mt < 4; ++mt)
#pragma unroll
                    for (int e = 0; e < 4; ++e)
                        P[(mt * 16 + lg * 4 + e) * 104 + 64 + lr] =
                            f2bf(accO[mt][e]);
            }
        }
        __syncthreads();

        // ---- phase 2: out = W_aug @ P  (reads only P + registers)
        {
            float* Ob = out + ((size_t)pair << 12);
#pragma unroll
            for (int nt = 0; nt < 4; ++nt) {
                const int i = nt * 16 + lr;
                bf16x8 bP[3];
#pragma unroll
                for (int ks = 0; ks < 3; ++ks)
                    bP[ks] = *(const bf16x8*)(P + i * 104 + ks * 32 + lg * 8);
                f32x4 acc = (f32x4){0.f, 0.f, 0.f, 0.f};
#pragma unroll
                for (int ks = 0; ks < 3; ++ks)
                    acc = MFMA16(afw[ks], bP[ks], acc);         // D[o][i]
                *(f32x4*)(Ob + i * 64 + w * 16 + lg * 4) = acc;
            }
        }
        // ---- stage next pair (safe: phase2 reads only P)
        if (pp < 3) {
            bf16x8 xrA = cvt8f(px0, px1);
            bf16x8 xrB = cvt8f(px2, px3);
            *(bf16x8*)(adjs + row0 * 72 + c8) = fuse8(sA, aA0, aA1, ab);
            *(bf16x8*)(adjs + row1 * 72 + c8) = fuse8(sB, aB0, aB1, ab);
#pragma unroll
            for (int d = 0; d < 8; ++d) {
                xT[(cx0 + d) * 72 + gx0 + jx]     = xrA[d];
                xT[(cx0 + 8 + d) * 72 + gx0 + jx] = xrB[d];
            }
        }
        __syncthreads();    // P-reads done before next phase1; LDS staged
    }
}

// ---------------------------------------------------------------------------
extern "C" void kernel_launch(void* const* d_in, const int* in_sizes, int n_in,
                              void* d_out, int out_size, void* d_ws, size_t ws_size,
                              hipStream_t stream)
{
    const float* x    = (const float*)d_in[0];
    const float* A    = (const float*)d_in[1];
    const float* w_m1 = (const float*)d_in[2];
    const float* b_m1 = (const float*)d_in[3];
    const float* w_m2 = (const float*)d_in[4];
    const float* b_m2 = (const float*)d_in[5];
    const float* w_rm = (const float*)d_in[6];
    const float* b_rm = (const float*)d_in[7];
    const float* w_f  = (const float*)d_in[8];
    const float* b_f  = (const float*)d_in[9];
    const int*   alpha = (const int*)d_in[10];

    // ws layout: adjm [0,33.5MB), m1T [34,36), m2T [36,38).
    char* ws = (char*)d_ws;
    short* adjm = (short*)(ws);
    float* m1T = (float*)(ws + (size_t)34 * 1024 * 1024);
    float* m2T = (float*)(ws + (size_t)36 * 1024 * 1024);
    float* out = (float*)d_out;

    k0_proj<<<dim3(512), dim3(512), 0, stream>>>(x, w_m1, b_m1, w_m2, b_m2,
                                                 m1T, m2T);
    k1_adj<<<dim3(512), dim3(512), 0, stream>>>(w_rm, m1T, m2T, alpha, adjm);
    k2_out<<<dim3(1024), dim3(256), 0, stream>>>(adjm, x, A, b_rm, alpha,
                                                 w_f, b_f, out);
}